// Round 5
// baseline (379.614 us; speedup 1.0000x reference)
//
#include <hip/hip_runtime.h>
#include <hip/hip_bf16.h>
#include <stdint.h>

typedef __attribute__((ext_vector_type(8))) short bf16x8;
typedef __attribute__((ext_vector_type(4))) float f32x4;
typedef __attribute__((ext_vector_type(8))) unsigned short ushort8;

__device__ __forceinline__ float bf2f(unsigned short u) {
  union { unsigned int i; float f; } x; x.i = ((unsigned int)u) << 16; return x.f;
}
__device__ __forceinline__ unsigned short f2bf(float f) {
  union { __hip_bfloat16 h; unsigned short u; } x; x.h = __float2bfloat16(f); return x.u;
}

__device__ __forceinline__ void gload_lds16(const void* g, void* l) {
  __builtin_amdgcn_global_load_lds((__attribute__((address_space(1))) const void*)g,
                                   (__attribute__((address_space(3))) void*)l, 16, 0, 0);
}

// ---------------- f32 -> bf16 convert (weights only, 12 MB total) ----------------
__global__ __launch_bounds__(256) void cvt3_kernel(const float* __restrict__ a,
                                                   const float* __restrict__ b,
                                                   const float* __restrict__ c,
                                                   unsigned short* __restrict__ oa,
                                                   unsigned short* __restrict__ ob,
                                                   unsigned short* __restrict__ oc,
                                                   int n8) {
  const float* in = blockIdx.y == 0 ? a : blockIdx.y == 1 ? b : c;
  unsigned short* out = blockIdx.y == 0 ? oa : blockIdx.y == 1 ? ob : oc;
  int i = blockIdx.x * 256 + threadIdx.x;
  if (i >= n8) return;
  const float4* p = (const float4*)(in + (size_t)i * 8);
  float4 x = p[0], y = p[1];
  ushort8 o;
  o[0] = f2bf(x.x); o[1] = f2bf(x.y); o[2] = f2bf(x.z); o[3] = f2bf(x.w);
  o[4] = f2bf(y.x); o[5] = f2bf(y.y); o[6] = f2bf(y.z); o[7] = f2bf(y.w);
  *(ushort8*)(out + (size_t)i * 8) = o;
}

// ======================================================================
// Shared GEMM body: C = A_f32[M,1024] @ B_bf16[1024,1024]^T (+bias)
// 128x128 tile, BK=32, 4 waves, 1-barrier double-buffer.
// A staged as f32 via global_load_lds with XOR-granule swizzle:
//   store: logical (row, g) -> phys (row, g ^ (row&7));  (16B granules, 8/row)
//   gload source granule for lane l: (l&7) ^ (l>>3)  (since row&7 == l>>3)
//   read:  logical granule (2*fkg+b) of row lr at phys ((2*fkg+b) ^ (lr&7))
// B staged bf16 via global_load_lds (round-2 proven layout).
// NORM=1: fused bias + per-head(64-col) L2 norm, bf16 C. NORM=0: bias + f32 C.
// ======================================================================
template <bool NORM>
__device__ __forceinline__ void gemm_f32a_body(
    const float* __restrict__ A,
    const unsigned short* __restrict__ B,
    const float* __restrict__ bias,
    void* __restrict__ C,
    int bm, int bn,
    float* __restrict__ AfBase,          // [2][128][32] f32
    unsigned short* __restrict__ BbBase) // [2][128][32] bf16
{
  const int tid = threadIdx.x, wid = tid >> 6, lane = tid & 63;
  const int wrow = (wid >> 1) * 64, wcol = (wid & 1) * 64;
  const int fr = lane & 15, fkg = lane >> 4;
  const int fk = fkg * 8, g4 = fkg * 4;
  const int pg0 = (2 * fkg) ^ (fr & 7);        // phys granule of logical 2*fkg
  const int srow = lane >> 3;                  // staging row-in-8
  const int sgran = (lane & 7) ^ srow;         // staging source granule

  f32x4 acc[4][4];
#pragma unroll
  for (int m = 0; m < 4; ++m)
#pragma unroll
    for (int n = 0; n < 4; ++n) acc[m][n] = (f32x4){0.f, 0.f, 0.f, 0.f};

  const size_t abase = (size_t)(bm * 128) * 1024;
  const size_t bbase = (size_t)(bn * 128) * 1024;

#define STAGE_AB(buf, kt)                                                         \
  _Pragma("unroll") for (int i = 0; i < 4; ++i) {                                 \
    gload_lds16(A + abase + (size_t)(wid * 32 + i * 8 + srow) * 1024 + (kt) + sgran * 4, \
                AfBase + (size_t)(buf) * 4096 + (wid * 32 + i * 8) * 32);         \
  }                                                                               \
  _Pragma("unroll") for (int it = 0; it < 2; ++it) {                              \
    const int chunk = wid * 2 + it;                                               \
    gload_lds16(B + bbase + (size_t)(chunk * 16 + (lane >> 2)) * 1024 + (kt) + (lane & 3) * 8, \
                BbBase + (size_t)(buf) * 4096 + chunk * 16 * 32);                 \
  }

  STAGE_AB(0, 0);
  __syncthreads();

  for (int t = 0; t < 32; ++t) {
    const int cur = t & 1;
    if (t < 31) { STAGE_AB(cur ^ 1, (t + 1) * 32); }
    bf16x8 af[4], bfv[4];
#pragma unroll
    for (int m = 0; m < 4; ++m) {
      const float* rp = AfBase + (size_t)cur * 4096 + (wrow + m * 16 + fr) * 32;
      float4 lo = *(const float4*)(rp + pg0 * 4);
      float4 hi = *(const float4*)(rp + (pg0 ^ 1) * 4);
      bf16x8 tv;
      tv[0] = (short)f2bf(lo.x); tv[1] = (short)f2bf(lo.y);
      tv[2] = (short)f2bf(lo.z); tv[3] = (short)f2bf(lo.w);
      tv[4] = (short)f2bf(hi.x); tv[5] = (short)f2bf(hi.y);
      tv[6] = (short)f2bf(hi.z); tv[7] = (short)f2bf(hi.w);
      af[m] = tv;
    }
#pragma unroll
    for (int n = 0; n < 4; ++n)
      bfv[n] = *(const bf16x8*)(BbBase + (size_t)cur * 4096 + (wcol + n * 16 + fr) * 32 + fk);
#pragma unroll
    for (int m = 0; m < 4; ++m)
#pragma unroll
      for (int n = 0; n < 4; ++n)
        acc[m][n] = __builtin_amdgcn_mfma_f32_16x16x32_bf16(af[m], bfv[n], acc[m][n], 0, 0, 0);
    __syncthreads();
  }
#undef STAGE_AB

  if (NORM) {
    // bias + per-row L2 norm over this wave's 64-col head block, bf16 out
    float bsv[4];
#pragma unroll
    for (int n = 0; n < 4; ++n) bsv[n] = bias[bn * 128 + wcol + n * 16 + fr];
#pragma unroll
    for (int m = 0; m < 4; ++m) {
      float val[4][4];
      float inv[4];
#pragma unroll
      for (int j = 0; j < 4; ++j) {
        float s = 0.f;
#pragma unroll
        for (int n = 0; n < 4; ++n) {
          val[n][j] = acc[m][n][j] + bsv[n];
          s += val[n][j] * val[n][j];
        }
        s += __shfl_xor(s, 1); s += __shfl_xor(s, 2);
        s += __shfl_xor(s, 4); s += __shfl_xor(s, 8);
        inv[j] = 1.f / fmaxf(sqrtf(s), 1e-12f);
      }
#pragma unroll
      for (int n = 0; n < 4; ++n) {
        const int col = bn * 128 + wcol + n * 16 + fr;
#pragma unroll
        for (int j = 0; j < 4; ++j) {
          const int row = bm * 128 + wrow + m * 16 + g4 + j;
          ((unsigned short*)C)[(size_t)row * 1024 + col] = f2bf(val[n][j] * inv[j]);
        }
      }
    }
  } else {
#pragma unroll
    for (int n = 0; n < 4; ++n) {
      const int col = bn * 128 + wcol + n * 16 + fr;
      const float bsv = bias[col];
#pragma unroll
      for (int m = 0; m < 4; ++m) {
#pragma unroll
        for (int j = 0; j < 4; ++j) {
          const int row = bm * 128 + wrow + m * 16 + g4 + j;
          ((float*)C)[(size_t)row * 1024 + col] = acc[m][n][j] + bsv;
        }
      }
    }
  }
}

// ---------------- proj pair: kh = norm(k@Wk^T+bk), vh = norm(v@Wv^T+bv) ----------------
__global__ __launch_bounds__(256) void proj_norm_kernel(
    const float* __restrict__ A0, const float* __restrict__ A1,
    const unsigned short* __restrict__ B0, const unsigned short* __restrict__ B1,
    const float* __restrict__ bias0, const float* __restrict__ bias1,
    unsigned short* __restrict__ C0, unsigned short* __restrict__ C1) {
  __shared__ float Af[2][128][32];
  __shared__ unsigned short Bb[2][128][32];
  const int flat = (blockIdx.z * 128 + blockIdx.y) * 8 + blockIdx.x;  // 2048
  const int swz = (flat & 7) * 256 + (flat >> 3);                     // bijective
  const int zz = swz >> 10;
  const int rem = swz & 1023;
  const int bm = rem >> 3, bn = rem & 7;
  gemm_f32a_body<true>(zz ? A1 : A0, zz ? B1 : B0, zz ? bias1 : bias0,
                       zz ? (void*)C1 : (void*)C0, bm, bn,
                       &Af[0][0][0], &Bb[0][0][0]);
}

// ---------------- final: out = q @ Beff_b^T + beff_b (f32 out) ----------------
__global__ __launch_bounds__(256) void final_gemm_kernel(
    const float* __restrict__ A,              // q f32 [16384][1024]
    const unsigned short* __restrict__ Beff,  // [4][1024][1024] bf16
    const float* __restrict__ beff,           // [4][1024]
    float* __restrict__ out) {
  __shared__ float Af[2][128][32];
  __shared__ unsigned short Bb[2][128][32];
  const int flat = blockIdx.y * 8 + blockIdx.x;  // 1024
  const int swz = (flat & 7) * 128 + (flat >> 3);
  const int bm = swz >> 3, bn = swz & 7;
  const int b = bm >> 5;
  gemm_f32a_body<false>(A, Beff + (size_t)b * 1048576, beff + b * 1024, out, bm, bn,
                        &Af[0][0][0], &Bb[0][0][0]);
}

// ============ kv partials: kvp[chunk][b*16+h][i][j] = sum_{s in chunk} kh[s][i]*vh[s][j] ============
__global__ __launch_bounds__(256) void kv_part_kernel(const unsigned short* __restrict__ kh,
                                                      const unsigned short* __restrict__ vh,
                                                      float* __restrict__ kvp) {
  const int chunk = blockIdx.x, h = blockIdx.y, b = blockIdx.z;
  __shared__ unsigned short khT[64][264];
  __shared__ unsigned short vhT[64][264];
  const int tid = threadIdx.x, wid = tid >> 6, lane = tid & 63;
  const int fr = lane & 15, fk = (lane >> 4) * 8, g4 = (lane >> 4) * 4;

  const int jb = tid & 7, sb = tid >> 3;
  const size_t base = ((size_t)b * 4096 + chunk * 256) * 1024 + h * 64;
  {
    ushort8 rk[8], rv[8];
#pragma unroll
    for (int u = 0; u < 8; ++u) {
      rk[u] = *(const ushort8*)(kh + base + (size_t)(sb * 8 + u) * 1024 + jb * 8);
      rv[u] = *(const ushort8*)(vh + base + (size_t)(sb * 8 + u) * 1024 + jb * 8);
    }
#pragma unroll
    for (int jj = 0; jj < 8; ++jj) {
      ushort8 ck, cv;
#pragma unroll
      for (int u = 0; u < 8; ++u) { ck[u] = rk[u][jj]; cv[u] = rv[u][jj]; }
      *(ushort8*)&khT[jb * 8 + jj][sb * 8] = ck;
      *(ushort8*)&vhT[jb * 8 + jj][sb * 8] = cv;
    }
  }
  __syncthreads();

  f32x4 acc2[4];
#pragma unroll
  for (int n = 0; n < 4; ++n) acc2[n] = (f32x4){0.f, 0.f, 0.f, 0.f};
#pragma unroll
  for (int ks = 0; ks < 8; ++ks) {
    bf16x8 a2 = *(const bf16x8*)&khT[wid * 16 + fr][ks * 32 + fk];
    bf16x8 b2[4];
#pragma unroll
    for (int jt = 0; jt < 4; ++jt) b2[jt] = *(const bf16x8*)&vhT[jt * 16 + fr][ks * 32 + fk];
#pragma unroll
    for (int jt = 0; jt < 4; ++jt)
      acc2[jt] = __builtin_amdgcn_mfma_f32_16x16x32_bf16(a2, b2[jt], acc2[jt], 0, 0, 0);
  }
  float* dst = kvp + ((size_t)chunk * 64 + b * 16 + h) * 4096;
#pragma unroll
  for (int jt = 0; jt < 4; ++jt)
#pragma unroll
    for (int jj = 0; jj < 4; ++jj)
      dst[(wid * 16 + g4 + jj) * 64 + jt * 16 + fr] = acc2[jt][jj];
}

// ============ weff (+fused chunk reduce): Beff[b][h*64+j][d] = sum_i Wq[h*64+i][d]*kv[b,h,i,j] ============
__global__ __launch_bounds__(256) void weff_kernel(
    const unsigned short* __restrict__ Wq,   // bf16 [1024][1024]
    const float* __restrict__ bq,            // [1024]
    const float* __restrict__ kvp,           // [16][64][64][64] f32 partials
    unsigned short* __restrict__ Beff,       // [4][1024][1024] bf16
    float* __restrict__ beff) {              // [4][1024]
  const int dt = blockIdx.x, h = blockIdx.y, b = blockIdx.z;
  __shared__ float kvS[64 * 64];
  __shared__ float WqF[64 * 128];
  const int tid = threadIdx.x;

  const float* kvsrc = kvp + (size_t)(b * 16 + h) * 4096;
  for (int e = tid; e < 4096; e += 256) {
    float s = 0.f;
#pragma unroll
    for (int c = 0; c < 16; ++c) s += kvsrc[(size_t)c * 64 * 4096 + e];
    kvS[e] = s;
  }
  {
    int i = tid >> 2, dseg = tid & 3;
    const unsigned short* src = Wq + (size_t)(h * 64 + i) * 1024 + dt * 128 + dseg * 32;
    float* dst = &WqF[i * 128 + dseg * 32];
#pragma unroll
    for (int w = 0; w < 4; ++w) {
      ushort8 vv = ((const ushort8*)src)[w];
#pragma unroll
      for (int u = 0; u < 8; ++u) dst[w * 8 + u] = bf2f(vv[u]);
    }
  }
  __syncthreads();

  const int tj = tid & 63, tg = tid >> 6;
  float o[32];
#pragma unroll
  for (int dd = 0; dd < 32; ++dd) o[dd] = 0.f;
  for (int i = 0; i < 64; ++i) {
    float kvv = kvS[i * 64 + tj];
    const float* wr = &WqF[i * 128 + tg * 32];
#pragma unroll
    for (int dd = 0; dd < 32; ++dd) o[dd] += wr[dd] * kvv;
  }
  unsigned short* dstB = Beff + ((size_t)(b * 1024 + h * 64 + tj)) * 1024 + dt * 128 + tg * 32;
#pragma unroll
  for (int w = 0; w < 4; ++w) {
    ushort8 ov;
#pragma unroll
    for (int u = 0; u < 8; ++u) ov[u] = f2bf(o[w * 8 + u]);
    ((ushort8*)dstB)[w] = ov;
  }
  if (tg == 0 && dt == 0) {
    float s = 0.f;
    for (int i = 0; i < 64; ++i) s += bq[h * 64 + i] * kvS[i * 64 + tj];
    beff[b * 1024 + h * 64 + tj] = s;
  }
}

extern "C" void kernel_launch(void* const* d_in, const int* in_sizes, int n_in,
                              void* d_out, int out_size, void* d_ws, size_t ws_size,
                              hipStream_t stream) {
  const float* q = (const float*)d_in[0];
  const float* k = (const float*)d_in[1];
  const float* v = (const float*)d_in[2];
  const float* Wq = (const float*)d_in[3];
  const float* bq = (const float*)d_in[4];
  const float* Wk = (const float*)d_in[5];
  const float* bk = (const float*)d_in[6];
  const float* Wv = (const float*)d_in[7];
  const float* bv = (const float*)d_in[8];
  float* out = (float*)d_out;

  char* ws = (char*)d_ws;
  const size_t MB = 1048576;
  unsigned short* kh = (unsigned short*)(ws + 0 * MB);      // 32 MB
  unsigned short* vh = (unsigned short*)(ws + 32 * MB);     // 32 MB
  unsigned short* Beff = (unsigned short*)(ws + 64 * MB);   // 8 MB
  unsigned short* Wqb = (unsigned short*)(ws + 72 * MB);    // 2 MB
  unsigned short* Wkb = (unsigned short*)(ws + 74 * MB);    // 2 MB
  unsigned short* Wvb = (unsigned short*)(ws + 76 * MB);    // 2 MB
  float* kvp = (float*)(ws + 78 * MB);                      // 16 MB
  float* beff = (float*)(ws + 94 * MB);                     // 16 KB

  // 1) weights -> bf16 (tiny)
  cvt3_kernel<<<dim3(512, 3), 256, 0, stream>>>(Wq, Wk, Wv, Wqb, Wkb, Wvb, 131072);

  // 2) projections + bias + L2 norm, reading f32 k/v directly via swizzled global_load_lds
  proj_norm_kernel<<<dim3(8, 128, 2), 256, 0, stream>>>(k, v, Wkb, Wvb, bk, bv, kh, vh);

  // 3) kv chunk partials (deterministic, no atomics)
  kv_part_kernel<<<dim3(16, 16, 4), 256, 0, stream>>>(kh, vh, kvp);

  // 4) weff: fused chunk-reduce + Wq-fold -> Beff bf16, beff
  weff_kernel<<<dim3(8, 16, 4), 256, 0, stream>>>(Wqb, bq, kvp, Beff, beff);

  // 5) out = q @ Beff^T + beff, reading f32 q directly
  final_gemm_kernel<<<dim3(8, 128), 256, 0, stream>>>(q, Beff, beff, out);
}

// Round 6
// 266.197 us; speedup vs baseline: 1.4261x; 1.4261x over previous
//
#include <hip/hip_runtime.h>
#include <hip/hip_bf16.h>
#include <stdint.h>

typedef __attribute__((ext_vector_type(8))) short bf16x8;
typedef __attribute__((ext_vector_type(4))) float f32x4;
typedef __attribute__((ext_vector_type(8))) unsigned short ushort8;

__device__ __forceinline__ float bf2f(unsigned short u) {
  union { unsigned int i; float f; } x; x.i = ((unsigned int)u) << 16; return x.f;
}
__device__ __forceinline__ unsigned short f2bf(float f) {
  union { __hip_bfloat16 h; unsigned short u; } x; x.h = __float2bfloat16(f); return x.u;
}

__device__ __forceinline__ void gload_lds16(const void* g, void* l) {
  __builtin_amdgcn_global_load_lds((__attribute__((address_space(1))) const void*)g,
                                   (__attribute__((address_space(3))) void*)l, 16, 0, 0);
}

// ---------------- f32 -> bf16 converts ----------------
__global__ __launch_bounds__(256) void cvt_kernel(const float* __restrict__ in,
                                                  unsigned short* __restrict__ out,
                                                  int n8) {
  int i = blockIdx.x * 256 + threadIdx.x;
  if (i >= n8) return;
  const float4* p = (const float4*)(in + (size_t)i * 8);
  float4 a = p[0], b = p[1];
  ushort8 o;
  o[0] = f2bf(a.x); o[1] = f2bf(a.y); o[2] = f2bf(a.z); o[3] = f2bf(a.w);
  o[4] = f2bf(b.x); o[5] = f2bf(b.y); o[6] = f2bf(b.z); o[7] = f2bf(b.w);
  *(ushort8*)(out + (size_t)i * 8) = o;
}

__global__ __launch_bounds__(256) void cvt2_kernel(const float* __restrict__ a,
                                                   const float* __restrict__ b,
                                                   unsigned short* __restrict__ oa,
                                                   unsigned short* __restrict__ ob,
                                                   int n8) {
  const float* in = blockIdx.y ? b : a;
  unsigned short* out = blockIdx.y ? ob : oa;
  int i = blockIdx.x * 256 + threadIdx.x;
  if (i >= n8) return;
  const float4* p = (const float4*)(in + (size_t)i * 8);
  float4 x = p[0], y = p[1];
  ushort8 o;
  o[0] = f2bf(x.x); o[1] = f2bf(x.y); o[2] = f2bf(x.z); o[3] = f2bf(x.w);
  o[4] = f2bf(y.x); o[5] = f2bf(y.y); o[6] = f2bf(y.z); o[7] = f2bf(y.w);
  *(ushort8*)(out + (size_t)i * 8) = o;
}

__global__ __launch_bounds__(256) void cvt3w_kernel(const float* __restrict__ a,
                                                    const float* __restrict__ b,
                                                    const float* __restrict__ c,
                                                    unsigned short* __restrict__ oa,
                                                    unsigned short* __restrict__ ob,
                                                    unsigned short* __restrict__ oc,
                                                    int n8) {
  const float* in = blockIdx.y == 0 ? a : blockIdx.y == 1 ? b : c;
  unsigned short* out = blockIdx.y == 0 ? oa : blockIdx.y == 1 ? ob : oc;
  int i = blockIdx.x * 256 + threadIdx.x;
  if (i >= n8) return;
  const float4* p = (const float4*)(in + (size_t)i * 8);
  float4 x = p[0], y = p[1];
  ushort8 o;
  o[0] = f2bf(x.x); o[1] = f2bf(x.y); o[2] = f2bf(x.z); o[3] = f2bf(x.w);
  o[4] = f2bf(y.x); o[5] = f2bf(y.y); o[6] = f2bf(y.z); o[7] = f2bf(y.w);
  *(ushort8*)(out + (size_t)i * 8) = o;
}

// ======================================================================
// GEMM body (PROVEN round-2 structure + round-3 1-barrier dbuf):
// C = A_bf16[M,1024] @ B_bf16[1024,1024]^T (+bias)
// 128x128 tile, BK=32, 4 waves, global_load_lds width-16 staging.
// NORM=1: fused bias + per-head(64-col) L2 norm, bf16 C.
// NORM=0: bias + f32 C.
// ======================================================================
template <bool NORM>
__device__ __forceinline__ void gemm_bf16_body(
    const unsigned short* __restrict__ A,
    const unsigned short* __restrict__ B,
    const float* __restrict__ bias,
    void* __restrict__ C,
    int bm, int bn,
    unsigned short (*Ab)[128][32], unsigned short (*Bb)[128][32]) {
  const int tid = threadIdx.x, wid = tid >> 6, lane = tid & 63;
  const int wrow = (wid >> 1) * 64, wcol = (wid & 1) * 64;
  const int fr = lane & 15, fk = (lane >> 4) * 8, g4 = (lane >> 4) * 4;

  f32x4 acc[4][4];
#pragma unroll
  for (int m = 0; m < 4; ++m)
#pragma unroll
    for (int n = 0; n < 4; ++n) acc[m][n] = (f32x4){0.f, 0.f, 0.f, 0.f};

  const size_t abase = (size_t)(bm * 128) * 1024;
  const size_t bbase = (size_t)(bn * 128) * 1024;

#define STG(buf, kt)                                                                     \
  _Pragma("unroll") for (int it = 0; it < 2; ++it) {                                     \
    const int chunk = wid * 2 + it;                                                      \
    gload_lds16(A + abase + (size_t)(chunk * 16 + (lane >> 2)) * 1024 + (kt) + (lane & 3) * 8, \
                &Ab[buf][chunk * 16][0]);                                                \
    gload_lds16(B + bbase + (size_t)(chunk * 16 + (lane >> 2)) * 1024 + (kt) + (lane & 3) * 8, \
                &Bb[buf][chunk * 16][0]);                                                \
  }

  STG(0, 0);
  __syncthreads();

  for (int t = 0; t < 32; ++t) {
    const int cur = t & 1;
    if (t < 31) { STG(cur ^ 1, (t + 1) * 32); }
    bf16x8 af[4], bfv[4];
#pragma unroll
    for (int m = 0; m < 4; ++m) af[m] = *(const bf16x8*)&Ab[cur][wrow + m * 16 + fr][fk];
#pragma unroll
    for (int n = 0; n < 4; ++n) bfv[n] = *(const bf16x8*)&Bb[cur][wcol + n * 16 + fr][fk];
#pragma unroll
    for (int m = 0; m < 4; ++m)
#pragma unroll
      for (int n = 0; n < 4; ++n)
        acc[m][n] = __builtin_amdgcn_mfma_f32_16x16x32_bf16(af[m], bfv[n], acc[m][n], 0, 0, 0);
    __syncthreads();
  }
#undef STG

  if (NORM) {
    float bsv[4];
#pragma unroll
    for (int n = 0; n < 4; ++n) bsv[n] = bias[bn * 128 + wcol + n * 16 + fr];
#pragma unroll
    for (int m = 0; m < 4; ++m) {
      float val[4][4];  // [n][j]
      float inv[4];
#pragma unroll
      for (int j = 0; j < 4; ++j) {
        float s = 0.f;
#pragma unroll
        for (int n = 0; n < 4; ++n) {
          val[n][j] = acc[m][n][j] + bsv[n];
          s += val[n][j] * val[n][j];
        }
        s += __shfl_xor(s, 1); s += __shfl_xor(s, 2);
        s += __shfl_xor(s, 4); s += __shfl_xor(s, 8);
        inv[j] = 1.f / fmaxf(sqrtf(s), 1e-12f);
      }
#pragma unroll
      for (int n = 0; n < 4; ++n) {
        const int col = bn * 128 + wcol + n * 16 + fr;
#pragma unroll
        for (int j = 0; j < 4; ++j) {
          const int row = bm * 128 + wrow + m * 16 + g4 + j;
          ((unsigned short*)C)[(size_t)row * 1024 + col] = f2bf(val[n][j] * inv[j]);
        }
      }
    }
  } else {
#pragma unroll
    for (int n = 0; n < 4; ++n) {
      const int col = bn * 128 + wcol + n * 16 + fr;
      const float bsv = bias[col];
#pragma unroll
      for (int m = 0; m < 4; ++m) {
#pragma unroll
        for (int j = 0; j < 4; ++j) {
          const int row = bm * 128 + wrow + m * 16 + g4 + j;
          ((float*)C)[(size_t)row * 1024 + col] = acc[m][n][j] + bsv;
        }
      }
    }
  }
}

// ---------------- proj pair: kh = norm(k@Wk^T+bk), vh = norm(v@Wv^T+bv) ----------------
__global__ __launch_bounds__(256) void proj_norm_kernel(
    const unsigned short* __restrict__ A0, const unsigned short* __restrict__ A1,
    const unsigned short* __restrict__ B0, const unsigned short* __restrict__ B1,
    const float* __restrict__ bias0, const float* __restrict__ bias1,
    unsigned short* __restrict__ C0, unsigned short* __restrict__ C1) {
  __shared__ unsigned short Ab[2][128][32];
  __shared__ unsigned short Bb[2][128][32];
  const int flat = (blockIdx.z * 128 + blockIdx.y) * 8 + blockIdx.x;  // 2048, %8==0
  const int swz = (flat & 7) * 256 + (flat >> 3);                     // bijective
  const int zz = swz >> 10;
  const int rem = swz & 1023;
  const int bm = rem >> 3, bn = rem & 7;
  gemm_bf16_body<true>(zz ? A1 : A0, zz ? B1 : B0, zz ? bias1 : bias0,
                       zz ? (void*)C1 : (void*)C0, bm, bn, Ab, Bb);
}

// ---------------- final: out = q_bf @ Beff_b^T + beff_b (f32 out) ----------------
__global__ __launch_bounds__(256) void final_gemm_kernel(
    const unsigned short* __restrict__ A,     // q_bf [16384][1024]
    const unsigned short* __restrict__ Beff,  // [4][1024][1024] bf16
    const float* __restrict__ beff,           // [4][1024]
    float* __restrict__ out) {
  __shared__ unsigned short Ab[2][128][32];
  __shared__ unsigned short Bb[2][128][32];
  const int flat = blockIdx.y * 8 + blockIdx.x;  // 1024
  const int swz = (flat & 7) * 128 + (flat >> 3);
  const int bm = swz >> 3, bn = swz & 7;
  const int b = bm >> 5;
  gemm_bf16_body<false>(A, Beff + (size_t)b * 1048576, beff + b * 1024, out, bm, bn, Ab, Bb);
}

// ============ kv partials: kvp[chunk][b*16+h][i][j] = sum_{s in chunk} kh[s][i]*vh[s][j] ============
__global__ __launch_bounds__(256) void kv_part_kernel(const unsigned short* __restrict__ kh,
                                                      const unsigned short* __restrict__ vh,
                                                      float* __restrict__ kvp) {
  const int chunk = blockIdx.x, h = blockIdx.y, b = blockIdx.z;
  __shared__ unsigned short khT[64][264];
  __shared__ unsigned short vhT[64][264];
  const int tid = threadIdx.x, wid = tid >> 6, lane = tid & 63;
  const int fr = lane & 15, fk = (lane >> 4) * 8, g4 = (lane >> 4) * 4;

  const int jb = tid & 7, sb = tid >> 3;
  const size_t base = ((size_t)b * 4096 + chunk * 256) * 1024 + h * 64;
  {
    ushort8 rk[8], rv[8];
#pragma unroll
    for (int u = 0; u < 8; ++u) {
      rk[u] = *(const ushort8*)(kh + base + (size_t)(sb * 8 + u) * 1024 + jb * 8);
      rv[u] = *(const ushort8*)(vh + base + (size_t)(sb * 8 + u) * 1024 + jb * 8);
    }
#pragma unroll
    for (int jj = 0; jj < 8; ++jj) {
      ushort8 ck, cv;
#pragma unroll
      for (int u = 0; u < 8; ++u) { ck[u] = rk[u][jj]; cv[u] = rv[u][jj]; }
      *(ushort8*)&khT[jb * 8 + jj][sb * 8] = ck;
      *(ushort8*)&vhT[jb * 8 + jj][sb * 8] = cv;
    }
  }
  __syncthreads();

  f32x4 acc2[4];
#pragma unroll
  for (int n = 0; n < 4; ++n) acc2[n] = (f32x4){0.f, 0.f, 0.f, 0.f};
#pragma unroll
  for (int ks = 0; ks < 8; ++ks) {
    bf16x8 a2 = *(const bf16x8*)&khT[wid * 16 + fr][ks * 32 + fk];
    bf16x8 b2[4];
#pragma unroll
    for (int jt = 0; jt < 4; ++jt) b2[jt] = *(const bf16x8*)&vhT[jt * 16 + fr][ks * 32 + fk];
#pragma unroll
    for (int jt = 0; jt < 4; ++jt)
      acc2[jt] = __builtin_amdgcn_mfma_f32_16x16x32_bf16(a2, b2[jt], acc2[jt], 0, 0, 0);
  }
  float* dst = kvp + ((size_t)chunk * 64 + b * 16 + h) * 4096;
#pragma unroll
  for (int jt = 0; jt < 4; ++jt)
#pragma unroll
    for (int jj = 0; jj < 4; ++jj)
      dst[(wid * 16 + g4 + jj) * 64 + jt * 16 + fr] = acc2[jt][jj];
}

// ============ weff (+fused chunk reduce): Beff[b][h*64+j][d] = sum_i Wq[h*64+i][d]*kv[b,h,i,j] ============
__global__ __launch_bounds__(256) void weff_kernel(
    const unsigned short* __restrict__ Wq,   // bf16 [1024][1024]
    const float* __restrict__ bq,            // [1024]
    const float* __restrict__ kvp,           // [16][64][64][64] f32 partials
    unsigned short* __restrict__ Beff,       // [4][1024][1024] bf16
    float* __restrict__ beff) {              // [4][1024]
  const int dt = blockIdx.x, h = blockIdx.y, b = blockIdx.z;
  __shared__ float kvS[64 * 64];
  __shared__ float WqF[64 * 128];
  const int tid = threadIdx.x;

  const float* kvsrc = kvp + (size_t)(b * 16 + h) * 4096;
  for (int e = tid; e < 4096; e += 256) {
    float s = 0.f;
#pragma unroll
    for (int c = 0; c < 16; ++c) s += kvsrc[(size_t)c * 64 * 4096 + e];
    kvS[e] = s;
  }
  {
    int i = tid >> 2, dseg = tid & 3;
    const unsigned short* src = Wq + (size_t)(h * 64 + i) * 1024 + dt * 128 + dseg * 32;
    float* dst = &WqF[i * 128 + dseg * 32];
#pragma unroll
    for (int w = 0; w < 4; ++w) {
      ushort8 vv = ((const ushort8*)src)[w];
#pragma unroll
      for (int u = 0; u < 8; ++u) dst[w * 8 + u] = bf2f(vv[u]);
    }
  }
  __syncthreads();

  const int tj = tid & 63, tg = tid >> 6;
  float o[32];
#pragma unroll
  for (int dd = 0; dd < 32; ++dd) o[dd] = 0.f;
  for (int i = 0; i < 64; ++i) {
    float kvv = kvS[i * 64 + tj];
    const float* wr = &WqF[i * 128 + tg * 32];
#pragma unroll
    for (int dd = 0; dd < 32; ++dd) o[dd] += wr[dd] * kvv;
  }
  unsigned short* dstB = Beff + ((size_t)(b * 1024 + h * 64 + tj)) * 1024 + dt * 128 + tg * 32;
#pragma unroll
  for (int w = 0; w < 4; ++w) {
    ushort8 ov;
#pragma unroll
    for (int u = 0; u < 8; ++u) ov[u] = f2bf(o[w * 8 + u]);
    ((ushort8*)dstB)[w] = ov;
  }
  if (tg == 0 && dt == 0) {
    float s = 0.f;
    for (int i = 0; i < 64; ++i) s += bq[h * 64 + i] * kvS[i * 64 + tj];
    beff[b * 1024 + h * 64 + tj] = s;
  }
}

extern "C" void kernel_launch(void* const* d_in, const int* in_sizes, int n_in,
                              void* d_out, int out_size, void* d_ws, size_t ws_size,
                              hipStream_t stream) {
  const float* q = (const float*)d_in[0];
  const float* k = (const float*)d_in[1];
  const float* v = (const float*)d_in[2];
  const float* Wq = (const float*)d_in[3];
  const float* bq = (const float*)d_in[4];
  const float* Wk = (const float*)d_in[5];
  const float* bk = (const float*)d_in[6];
  const float* Wv = (const float*)d_in[7];
  const float* bv = (const float*)d_in[8];
  float* out = (float*)d_out;

  const size_t NE = (size_t)16384 * 1024;
  const size_t MB = 1048576;

  char* ws = (char*)d_ws;
  unsigned short* S0 = (unsigned short*)(ws + 0 * MB);    // k_bf; later kvp (16MB) + Beff (8MB @ +16MB)
  unsigned short* S1 = (unsigned short*)(ws + 32 * MB);   // v_bf; later q_bf
  unsigned short* kh = (unsigned short*)(ws + 64 * MB);   // 32 MB
  unsigned short* vh = (unsigned short*)(ws + 96 * MB);   // 32 MB
  unsigned short* Wqb = (unsigned short*)(ws + 128 * MB); // 2 MB
  unsigned short* Wkb = (unsigned short*)(ws + 130 * MB); // 2 MB
  unsigned short* Wvb = (unsigned short*)(ws + 132 * MB); // 2 MB
  float* beff = (float*)(ws + 134 * MB);                  // 16 KB
  float* kvp = (float*)S0;                                // 16 MB (k_bf dead by then)
  unsigned short* Beff = (unsigned short*)(ws + 16 * MB); // 8 MB (upper half of S0 slot)

  // 1) k,v and weights -> bf16
  cvt2_kernel<<<dim3(8192, 2), 256, 0, stream>>>(k, v, S0, S1, (int)(NE / 8));
  cvt3w_kernel<<<dim3(512, 3), 256, 0, stream>>>(Wq, Wk, Wv, Wqb, Wkb, Wvb, 131072);

  // 2) projections + bias + L2 norm (z=2 batched, XCD-swizzled, dbuf)
  proj_norm_kernel<<<dim3(8, 128, 2), 256, 0, stream>>>(S0, S1, Wkb, Wvb, bk, bv, kh, vh);

  // 3) q -> bf16 (into v_bf slot, now dead)
  cvt_kernel<<<8192, 256, 0, stream>>>(q, S1, (int)(NE / 8));

  // 4) kv chunk partials (deterministic, into k_bf slot, now dead)
  kv_part_kernel<<<dim3(16, 16, 4), 256, 0, stream>>>(kh, vh, kvp);

  // 5) weff: fused chunk-reduce + Wq-fold -> Beff bf16, beff
  weff_kernel<<<dim3(8, 16, 4), 256, 0, stream>>>(Wqb, bq, kvp, Beff, beff);

  // 6) out = q_bf @ Beff^T + beff (f32 out)
  final_gemm_kernel<<<dim3(8, 128), 256, 0, stream>>>(S1, Beff, beff, out);
}

// Round 7
// 252.959 us; speedup vs baseline: 1.5007x; 1.0523x over previous
//
#include <hip/hip_runtime.h>
#include <hip/hip_bf16.h>
#include <stdint.h>

typedef __attribute__((ext_vector_type(8))) short bf16x8;
typedef __attribute__((ext_vector_type(4))) float f32x4;
typedef __attribute__((ext_vector_type(8))) unsigned short ushort8;

__device__ __forceinline__ float bf2f(unsigned short u) {
  union { unsigned int i; float f; } x; x.i = ((unsigned int)u) << 16; return x.f;
}
__device__ __forceinline__ unsigned short f2bf(float f) {
  union { __hip_bfloat16 h; unsigned short u; } x; x.h = __float2bfloat16(f); return x.u;
}

__device__ __forceinline__ void gload_lds16(const void* g, void* l) {
  __builtin_amdgcn_global_load_lds((__attribute__((address_space(1))) const void*)g,
                                   (__attribute__((address_space(3))) void*)l, 16, 0, 0);
}

// ---------------- f32 -> bf16 converts ----------------
__global__ __launch_bounds__(256) void cvt_kernel(const float* __restrict__ in,
                                                  unsigned short* __restrict__ out,
                                                  int n8) {
  int i = blockIdx.x * 256 + threadIdx.x;
  if (i >= n8) return;
  const float4* p = (const float4*)(in + (size_t)i * 8);
  float4 a = p[0], b = p[1];
  ushort8 o;
  o[0] = f2bf(a.x); o[1] = f2bf(a.y); o[2] = f2bf(a.z); o[3] = f2bf(a.w);
  o[4] = f2bf(b.x); o[5] = f2bf(b.y); o[6] = f2bf(b.z); o[7] = f2bf(b.w);
  *(ushort8*)(out + (size_t)i * 8) = o;
}

__global__ __launch_bounds__(256) void cvt2_kernel(const float* __restrict__ a,
                                                   const float* __restrict__ b,
                                                   unsigned short* __restrict__ oa,
                                                   unsigned short* __restrict__ ob,
                                                   int n8) {
  const float* in = blockIdx.y ? b : a;
  unsigned short* out = blockIdx.y ? ob : oa;
  int i = blockIdx.x * 256 + threadIdx.x;
  if (i >= n8) return;
  const float4* p = (const float4*)(in + (size_t)i * 8);
  float4 x = p[0], y = p[1];
  ushort8 o;
  o[0] = f2bf(x.x); o[1] = f2bf(x.y); o[2] = f2bf(x.z); o[3] = f2bf(x.w);
  o[4] = f2bf(y.x); o[5] = f2bf(y.y); o[6] = f2bf(y.z); o[7] = f2bf(y.w);
  *(ushort8*)(out + (size_t)i * 8) = o;
}

__global__ __launch_bounds__(256) void cvt3w_kernel(const float* __restrict__ a,
                                                    const float* __restrict__ b,
                                                    const float* __restrict__ c,
                                                    unsigned short* __restrict__ oa,
                                                    unsigned short* __restrict__ ob,
                                                    unsigned short* __restrict__ oc,
                                                    int n8) {
  const float* in = blockIdx.y == 0 ? a : blockIdx.y == 1 ? b : c;
  unsigned short* out = blockIdx.y == 0 ? oa : blockIdx.y == 1 ? ob : oc;
  int i = blockIdx.x * 256 + threadIdx.x;
  if (i >= n8) return;
  const float4* p = (const float4*)(in + (size_t)i * 8);
  float4 x = p[0], y = p[1];
  ushort8 o;
  o[0] = f2bf(x.x); o[1] = f2bf(x.y); o[2] = f2bf(x.z); o[3] = f2bf(x.w);
  o[4] = f2bf(y.x); o[5] = f2bf(y.y); o[6] = f2bf(y.z); o[7] = f2bf(y.w);
  *(ushort8*)(out + (size_t)i * 8) = o;
}

// ======================================================================
// 256x256-tile GEMM body: C = A_bf16[M,1024] @ B_bf16[1024,1024]^T (+bias)
// BK=32, 512 threads = 8 waves (2 Mx4 N), per-wave output 128x64.
// 3-buffer LDS ring (96 KB), prefetch distance = 2 K-tiles,
// steady-state s_waitcnt vmcnt(4) (never 0), raw s_barrier.
// LDS swizzle: phys 16B-granule = logical ^ ((row>>1)&3); applied to
// global SOURCE of global_load_lds (linear dest) and to frag reads.
// NORM=1: fused bias + per-head(64-col) L2 norm, bf16 C. NORM=0: bias+f32 C.
// ======================================================================
template <bool NORM>
__device__ __forceinline__ void gemm256_body(
    const unsigned short* __restrict__ A,
    const unsigned short* __restrict__ B,
    const float* __restrict__ bias,
    void* __restrict__ C,
    int bm, int bn,
    unsigned short (*Ab)[256][32], unsigned short (*Bb)[256][32]) {
  const int tid = threadIdx.x;
  const int widx = tid >> 6;
  const int lane = tid & 63;
  const int wr = widx >> 2;          // 0..1 (128-row half)
  const int wc = widx & 3;           // 0..3 (64-col group = one head)
  const int fr = lane & 15, fkg = lane >> 4;
  const int g4 = fkg * 4;
  const int pgo = (fkg ^ ((fr >> 1) & 3)) * 8;       // swizzled frag granule (elems)
  const int gsrc = ((lane & 3) ^ ((lane >> 3) & 3)) * 8;  // swizzled source granule (elems)
  const int srow = lane >> 2;                        // staging row-in-16

  f32x4 acc[8][4];
#pragma unroll
  for (int m = 0; m < 8; ++m)
#pragma unroll
    for (int n = 0; n < 4; ++n) acc[m][n] = (f32x4){0.f, 0.f, 0.f, 0.f};

  const size_t abase = (size_t)(bm * 256) * 1024;
  const size_t bbase = (size_t)(bn * 256) * 1024;

#define STG256(kt, bi)                                                          \
  {                                                                             \
    _Pragma("unroll") for (int j = 0; j < 2; ++j) {                             \
      const int r0 = widx * 32 + j * 16;                                        \
      gload_lds16(A + abase + (size_t)(r0 + srow) * 1024 + (kt) * 32 + gsrc,    \
                  &Ab[bi][r0][0]);                                              \
      gload_lds16(B + bbase + (size_t)(r0 + srow) * 1024 + (kt) * 32 + gsrc,    \
                  &Bb[bi][r0][0]);                                              \
    }                                                                           \
  }

  // prologue: stage K-tiles 0 and 1; wait tile 0 (4 loads of tile 1 in flight)
  STG256(0, 0);
  STG256(1, 1);
  asm volatile("s_waitcnt vmcnt(4)" ::: "memory");
  __builtin_amdgcn_s_barrier();
  __builtin_amdgcn_sched_barrier(0);

  for (int kt = 0; kt < 32; ++kt) {
    const int bi = kt % 3;
    if (kt + 2 < 32) { STG256(kt + 2, (kt + 2) % 3); }

    bf16x8 af[8], bfv[4];
#pragma unroll
    for (int m = 0; m < 8; ++m)
      af[m] = *(const bf16x8*)&Ab[bi][wr * 128 + m * 16 + fr][pgo];
#pragma unroll
    for (int n = 0; n < 4; ++n)
      bfv[n] = *(const bf16x8*)&Bb[bi][wc * 64 + n * 16 + fr][pgo];

    __builtin_amdgcn_s_setprio(1);
#pragma unroll
    for (int m = 0; m < 8; ++m)
#pragma unroll
      for (int n = 0; n < 4; ++n)
        acc[m][n] = __builtin_amdgcn_mfma_f32_16x16x32_bf16(af[m], bfv[n], acc[m][n], 0, 0, 0);
    __builtin_amdgcn_s_setprio(0);

    if (kt + 2 < 32) {
      asm volatile("s_waitcnt vmcnt(4)" ::: "memory");
    } else {
      asm volatile("s_waitcnt vmcnt(0)" ::: "memory");
    }
    __builtin_amdgcn_s_barrier();
    __builtin_amdgcn_sched_barrier(0);
  }
#undef STG256

  if (NORM) {
    // bias + per-row L2 norm over this wave's 64-col head block, bf16 out
    float bsv[4];
#pragma unroll
    for (int n = 0; n < 4; ++n) bsv[n] = bias[bn * 256 + wc * 64 + n * 16 + fr];
#pragma unroll
    for (int m = 0; m < 8; ++m) {
      float val[4][4];  // [n][j]
      float inv[4];
#pragma unroll
      for (int j = 0; j < 4; ++j) {
        float s = 0.f;
#pragma unroll
        for (int n = 0; n < 4; ++n) {
          val[n][j] = acc[m][n][j] + bsv[n];
          s += val[n][j] * val[n][j];
        }
        s += __shfl_xor(s, 1); s += __shfl_xor(s, 2);
        s += __shfl_xor(s, 4); s += __shfl_xor(s, 8);
        inv[j] = 1.f / fmaxf(sqrtf(s), 1e-12f);
      }
#pragma unroll
      for (int n = 0; n < 4; ++n) {
        const int col = bn * 256 + wc * 64 + n * 16 + fr;
#pragma unroll
        for (int j = 0; j < 4; ++j) {
          const int row = bm * 256 + wr * 128 + m * 16 + g4 + j;
          ((unsigned short*)C)[(size_t)row * 1024 + col] = f2bf(val[n][j] * inv[j]);
        }
      }
    }
  } else {
#pragma unroll
    for (int n = 0; n < 4; ++n) {
      const int col = bn * 256 + wc * 64 + n * 16 + fr;
      const float bsv = bias[col];
#pragma unroll
      for (int m = 0; m < 8; ++m) {
#pragma unroll
        for (int j = 0; j < 4; ++j) {
          const int row = bm * 256 + wr * 128 + m * 16 + g4 + j;
          ((float*)C)[(size_t)row * 1024 + col] = acc[m][n][j] + bsv;
        }
      }
    }
  }
}

// ---------------- proj pair: kh = norm(k@Wk^T+bk), vh = norm(v@Wv^T+bv) ----------------
__global__ __launch_bounds__(512) void proj_norm_kernel(
    const unsigned short* __restrict__ A0, const unsigned short* __restrict__ A1,
    const unsigned short* __restrict__ B0, const unsigned short* __restrict__ B1,
    const float* __restrict__ bias0, const float* __restrict__ bias1,
    unsigned short* __restrict__ C0, unsigned short* __restrict__ C1) {
  __shared__ unsigned short Ab[3][256][32];
  __shared__ unsigned short Bb[3][256][32];
  const int flat = (blockIdx.z * 64 + blockIdx.y) * 4 + blockIdx.x;  // 512, %8==0
  const int swz = (flat & 7) * 64 + (flat >> 3);                     // bijective
  const int zz = swz >> 8;
  const int rem = swz & 255;
  const int bm = rem >> 2, bn = rem & 3;
  gemm256_body<true>(zz ? A1 : A0, zz ? B1 : B0, zz ? bias1 : bias0,
                     zz ? (void*)C1 : (void*)C0, bm, bn, Ab, Bb);
}

// ---------------- final: out = q_bf @ Beff_b^T + beff_b (f32 out) ----------------
__global__ __launch_bounds__(512) void final_gemm_kernel(
    const unsigned short* __restrict__ A,     // q_bf [16384][1024]
    const unsigned short* __restrict__ Beff,  // [4][1024][1024] bf16
    const float* __restrict__ beff,           // [4][1024]
    float* __restrict__ out) {
  __shared__ unsigned short Ab[3][256][32];
  __shared__ unsigned short Bb[3][256][32];
  const int flat = blockIdx.y * 4 + blockIdx.x;  // 256, %8==0
  const int swz = (flat & 7) * 32 + (flat >> 3);
  const int bm = swz >> 2, bn = swz & 3;
  const int b = bm >> 4;  // 16 row-tiles of 256 per batch
  gemm256_body<false>(A, Beff + (size_t)b * 1048576, beff + b * 1024, out, bm, bn, Ab, Bb);
}

// ============ kv partials: kvp[chunk][b*16+h][i][j] = sum_{s in chunk} kh[s][i]*vh[s][j] ============
__global__ __launch_bounds__(256) void kv_part_kernel(const unsigned short* __restrict__ kh,
                                                      const unsigned short* __restrict__ vh,
                                                      float* __restrict__ kvp) {
  const int chunk = blockIdx.x, h = blockIdx.y, b = blockIdx.z;
  __shared__ unsigned short khT[64][264];
  __shared__ unsigned short vhT[64][264];
  const int tid = threadIdx.x, wid = tid >> 6, lane = tid & 63;
  const int fr = lane & 15, fk = (lane >> 4) * 8, g4 = (lane >> 4) * 4;

  const int jb = tid & 7, sb = tid >> 3;
  const size_t base = ((size_t)b * 4096 + chunk * 256) * 1024 + h * 64;
  {
    ushort8 rk[8], rv[8];
#pragma unroll
    for (int u = 0; u < 8; ++u) {
      rk[u] = *(const ushort8*)(kh + base + (size_t)(sb * 8 + u) * 1024 + jb * 8);
      rv[u] = *(const ushort8*)(vh + base + (size_t)(sb * 8 + u) * 1024 + jb * 8);
    }
#pragma unroll
    for (int jj = 0; jj < 8; ++jj) {
      ushort8 ck, cv;
#pragma unroll
      for (int u = 0; u < 8; ++u) { ck[u] = rk[u][jj]; cv[u] = rv[u][jj]; }
      *(ushort8*)&khT[jb * 8 + jj][sb * 8] = ck;
      *(ushort8*)&vhT[jb * 8 + jj][sb * 8] = cv;
    }
  }
  __syncthreads();

  f32x4 acc2[4];
#pragma unroll
  for (int n = 0; n < 4; ++n) acc2[n] = (f32x4){0.f, 0.f, 0.f, 0.f};
#pragma unroll
  for (int ks = 0; ks < 8; ++ks) {
    bf16x8 a2 = *(const bf16x8*)&khT[wid * 16 + fr][ks * 32 + fk];
    bf16x8 b2[4];
#pragma unroll
    for (int jt = 0; jt < 4; ++jt) b2[jt] = *(const bf16x8*)&vhT[jt * 16 + fr][ks * 32 + fk];
#pragma unroll
    for (int jt = 0; jt < 4; ++jt)
      acc2[jt] = __builtin_amdgcn_mfma_f32_16x16x32_bf16(a2, b2[jt], acc2[jt], 0, 0, 0);
  }
  float* dst = kvp + ((size_t)chunk * 64 + b * 16 + h) * 4096;
#pragma unroll
  for (int jt = 0; jt < 4; ++jt)
#pragma unroll
    for (int jj = 0; jj < 4; ++jj)
      dst[(wid * 16 + g4 + jj) * 64 + jt * 16 + fr] = acc2[jt][jj];
}

// ============ weff (+fused chunk reduce): Beff[b][h*64+j][d] = sum_i Wq[h*64+i][d]*kv[b,h,i,j] ============
__global__ __launch_bounds__(256) void weff_kernel(
    const unsigned short* __restrict__ Wq,   // bf16 [1024][1024]
    const float* __restrict__ bq,            // [1024]
    const float* __restrict__ kvp,           // [16][64][64][64] f32 partials
    unsigned short* __restrict__ Beff,       // [4][1024][1024] bf16
    float* __restrict__ beff) {              // [4][1024]
  const int dt = blockIdx.x, h = blockIdx.y, b = blockIdx.z;
  __shared__ float kvS[64 * 64];
  __shared__ float WqF[64 * 128];
  const int tid = threadIdx.x;

  const float* kvsrc = kvp + (size_t)(b * 16 + h) * 4096;
  for (int e = tid; e < 4096; e += 256) {
    float s = 0.f;
#pragma unroll
    for (int c = 0; c < 16; ++c) s += kvsrc[(size_t)c * 64 * 4096 + e];
    kvS[e] = s;
  }
  {
    int i = tid >> 2, dseg = tid & 3;
    const unsigned short* src = Wq + (size_t)(h * 64 + i) * 1024 + dt * 128 + dseg * 32;
    float* dst = &WqF[i * 128 + dseg * 32];
#pragma unroll
    for (int w = 0; w < 4; ++w) {
      ushort8 vv = ((const ushort8*)src)[w];
#pragma unroll
      for (int u = 0; u < 8; ++u) dst[w * 8 + u] = bf2f(vv[u]);
    }
  }
  __syncthreads();

  const int tj = tid & 63, tg = tid >> 6;
  float o[32];
#pragma unroll
  for (int dd = 0; dd < 32; ++dd) o[dd] = 0.f;
  for (int i = 0; i < 64; ++i) {
    float kvv = kvS[i * 64 + tj];
    const float* wr = &WqF[i * 128 + tg * 32];
#pragma unroll
    for (int dd = 0; dd < 32; ++dd) o[dd] += wr[dd] * kvv;
  }
  unsigned short* dstB = Beff + ((size_t)(b * 1024 + h * 64 + tj)) * 1024 + dt * 128 + tg * 32;
#pragma unroll
  for (int w = 0; w < 4; ++w) {
    ushort8 ov;
#pragma unroll
    for (int u = 0; u < 8; ++u) ov[u] = f2bf(o[w * 8 + u]);
    ((ushort8*)dstB)[w] = ov;
  }
  if (tg == 0 && dt == 0) {
    float s = 0.f;
    for (int i = 0; i < 64; ++i) s += bq[h * 64 + i] * kvS[i * 64 + tj];
    beff[b * 1024 + h * 64 + tj] = s;
  }
}

extern "C" void kernel_launch(void* const* d_in, const int* in_sizes, int n_in,
                              void* d_out, int out_size, void* d_ws, size_t ws_size,
                              hipStream_t stream) {
  const float* q = (const float*)d_in[0];
  const float* k = (const float*)d_in[1];
  const float* v = (const float*)d_in[2];
  const float* Wq = (const float*)d_in[3];
  const float* bq = (const float*)d_in[4];
  const float* Wk = (const float*)d_in[5];
  const float* bk = (const float*)d_in[6];
  const float* Wv = (const float*)d_in[7];
  const float* bv = (const float*)d_in[8];
  float* out = (float*)d_out;

  const size_t NE = (size_t)16384 * 1024;
  const size_t MB = 1048576;

  char* ws = (char*)d_ws;
  unsigned short* S0 = (unsigned short*)(ws + 0 * MB);    // k_bf; later kvp (16MB) + Beff (8MB @ +16MB)
  unsigned short* S1 = (unsigned short*)(ws + 32 * MB);   // v_bf; later q_bf
  unsigned short* kh = (unsigned short*)(ws + 64 * MB);   // 32 MB
  unsigned short* vh = (unsigned short*)(ws + 96 * MB);   // 32 MB
  unsigned short* Wqb = (unsigned short*)(ws + 128 * MB); // 2 MB
  unsigned short* Wkb = (unsigned short*)(ws + 130 * MB); // 2 MB
  unsigned short* Wvb = (unsigned short*)(ws + 132 * MB); // 2 MB
  float* beff = (float*)(ws + 134 * MB);                  // 16 KB
  float* kvp = (float*)S0;                                // 16 MB (k_bf dead by then)
  unsigned short* Beff = (unsigned short*)(ws + 16 * MB); // 8 MB

  // 1) k,v and weights -> bf16
  cvt2_kernel<<<dim3(8192, 2), 256, 0, stream>>>(k, v, S0, S1, (int)(NE / 8));
  cvt3w_kernel<<<dim3(512, 3), 256, 0, stream>>>(Wq, Wk, Wv, Wqb, Wkb, Wvb, 131072);

  // 2) projections + bias + L2 norm (256^2 tiles, counted-vmcnt ring, XCD-swizzled)
  proj_norm_kernel<<<dim3(4, 64, 2), 512, 0, stream>>>(S0, S1, Wkb, Wvb, bk, bv, kh, vh);

  // 3) q -> bf16 (into v_bf slot, now dead)
  cvt_kernel<<<8192, 256, 0, stream>>>(q, S1, (int)(NE / 8));

  // 4) kv chunk partials (deterministic, into k_bf slot, now dead)
  kv_part_kernel<<<dim3(16, 16, 4), 256, 0, stream>>>(kh, vh, kvp);

  // 5) weff: fused chunk-reduce + Wq-fold -> Beff bf16, beff
  weff_kernel<<<dim3(8, 16, 4), 256, 0, stream>>>(Wqb, bq, kvp, Beff, beff);

  // 6) out = q_bf @ Beff^T + beff (f32 out, 256^2 tiles)
  final_gemm_kernel<<<dim3(4, 64), 512, 0, stream>>>(S1, Beff, beff, out);
}

// Round 8
// 238.654 us; speedup vs baseline: 1.5906x; 1.0599x over previous
//
#include <hip/hip_runtime.h>
#include <hip/hip_bf16.h>
#include <stdint.h>

typedef __attribute__((ext_vector_type(8))) short bf16x8;
typedef __attribute__((ext_vector_type(4))) float f32x4;
typedef __attribute__((ext_vector_type(8))) unsigned short ushort8;

__device__ __forceinline__ float bf2f(unsigned short u) {
  union { unsigned int i; float f; } x; x.i = ((unsigned int)u) << 16; return x.f;
}
__device__ __forceinline__ unsigned short f2bf(float f) {
  union { __hip_bfloat16 h; unsigned short u; } x; x.h = __float2bfloat16(f); return x.u;
}

__device__ __forceinline__ void gload_lds16(const void* g, void* l) {
  __builtin_amdgcn_global_load_lds((__attribute__((address_space(1))) const void*)g,
                                   (__attribute__((address_space(3))) void*)l, 16, 0, 0);
}

// ---------------- f32 -> bf16 converts ----------------
__global__ __launch_bounds__(256) void cvt_kernel(const float* __restrict__ in,
                                                  unsigned short* __restrict__ out,
                                                  int n8) {
  int i = blockIdx.x * 256 + threadIdx.x;
  if (i >= n8) return;
  const float4* p = (const float4*)(in + (size_t)i * 8);
  float4 a = p[0], b = p[1];
  ushort8 o;
  o[0] = f2bf(a.x); o[1] = f2bf(a.y); o[2] = f2bf(a.z); o[3] = f2bf(a.w);
  o[4] = f2bf(b.x); o[5] = f2bf(b.y); o[6] = f2bf(b.z); o[7] = f2bf(b.w);
  *(ushort8*)(out + (size_t)i * 8) = o;
}

__global__ __launch_bounds__(256) void cvt2_kernel(const float* __restrict__ a,
                                                   const float* __restrict__ b,
                                                   unsigned short* __restrict__ oa,
                                                   unsigned short* __restrict__ ob,
                                                   int n8) {
  const float* in = blockIdx.y ? b : a;
  unsigned short* out = blockIdx.y ? ob : oa;
  int i = blockIdx.x * 256 + threadIdx.x;
  if (i >= n8) return;
  const float4* p = (const float4*)(in + (size_t)i * 8);
  float4 x = p[0], y = p[1];
  ushort8 o;
  o[0] = f2bf(x.x); o[1] = f2bf(x.y); o[2] = f2bf(x.z); o[3] = f2bf(x.w);
  o[4] = f2bf(y.x); o[5] = f2bf(y.y); o[6] = f2bf(y.z); o[7] = f2bf(y.w);
  *(ushort8*)(out + (size_t)i * 8) = o;
}

__global__ __launch_bounds__(256) void cvt3w_kernel(const float* __restrict__ a,
                                                    const float* __restrict__ b,
                                                    const float* __restrict__ c,
                                                    unsigned short* __restrict__ oa,
                                                    unsigned short* __restrict__ ob,
                                                    unsigned short* __restrict__ oc,
                                                    int n8) {
  const float* in = blockIdx.y == 0 ? a : blockIdx.y == 1 ? b : c;
  unsigned short* out = blockIdx.y == 0 ? oa : blockIdx.y == 1 ? ob : oc;
  int i = blockIdx.x * 256 + threadIdx.x;
  if (i >= n8) return;
  const float4* p = (const float4*)(in + (size_t)i * 8);
  float4 x = p[0], y = p[1];
  ushort8 o;
  o[0] = f2bf(x.x); o[1] = f2bf(x.y); o[2] = f2bf(x.z); o[3] = f2bf(x.w);
  o[4] = f2bf(y.x); o[5] = f2bf(y.y); o[6] = f2bf(y.z); o[7] = f2bf(y.w);
  *(ushort8*)(out + (size_t)i * 8) = o;
}

// ======================================================================
// 8-phase 256x256 GEMM body: C = A_bf16[M,1024] @ B_bf16[1024,1024]^T (+bias)
// BK=64 split in 2 K-halves of 32; LDS As/Bs[buf2][ks2][256][32] = 128 KB.
// 8 waves (2M x 4N), per-wave out 128x64. Phase = (buf,ks,qn):
//   {ds_read frags || stage 1 quarter-tile} -> barrier -> 16 MFMA -> [vmcnt] -> barrier
// vmcnt(8) at even phases keeps 4 staged units (8 loads/wave) in flight.
// ======================================================================
template <bool NORM>
__device__ __forceinline__ void gemm256_body(
    const unsigned short* __restrict__ A,
    const unsigned short* __restrict__ B,
    const float* __restrict__ bias,
    void* __restrict__ C,
    int bm, int bn,
    unsigned short (*As)[256][32],  // [4] = buf*2+ks
    unsigned short (*Bs)[256][32]) {
  const int tid = threadIdx.x;
  const int widx = tid >> 6, lane = tid & 63;
  const int wr = widx >> 2, wc = widx & 3;
  const int fr = lane & 15, fkg = lane >> 4;
  const int g4 = fkg * 4;
  const int pgo = (fkg ^ (fr & 3)) * 8;            // swizzled read granule (elems)
  const int srow = lane >> 2;                      // staging row-in-16
  const int sg = ((lane & 3) ^ (srow & 3)) * 8;    // swizzled source granule (elems)

  const size_t abase = (size_t)(bm * 256) * 1024;
  const size_t bbase = (size_t)(bn * 256) * 1024;

  f32x4 acc[8][4];
#pragma unroll
  for (int m = 0; m < 8; ++m)
#pragma unroll
    for (int n = 0; n < 4; ++n) acc[m][n] = (f32x4){0.f, 0.f, 0.f, 0.f};

  bf16x8 aF[8], bF0, bF1;

#define STG_A(bufi, kh, kt)                                                                \
  {                                                                                        \
    gload_lds16(A + abase + (size_t)(widx * 16 + srow) * 1024 + (kt) * 64 + (kh) * 32 + sg,\
                &As[(bufi) * 2 + (kh)][widx * 16][0]);                                     \
    gload_lds16(A + abase + (size_t)(128 + widx * 16 + srow) * 1024 + (kt) * 64 + (kh) * 32 + sg, \
                &As[(bufi) * 2 + (kh)][128 + widx * 16][0]);                               \
  }
#define STG_B(bufi, kh, kt)                                                                \
  {                                                                                        \
    gload_lds16(B + bbase + (size_t)(widx * 16 + srow) * 1024 + (kt) * 64 + (kh) * 32 + sg,\
                &Bs[(bufi) * 2 + (kh)][widx * 16][0]);                                     \
    gload_lds16(B + bbase + (size_t)(128 + widx * 16 + srow) * 1024 + (kt) * 64 + (kh) * 32 + sg, \
                &Bs[(bufi) * 2 + (kh)][128 + widx * 16][0]);                               \
  }
#define LDA(bufi, ks)                                                                      \
  _Pragma("unroll") for (int m = 0; m < 8; ++m)                                            \
      aF[m] = *(const bf16x8*)&As[(bufi) * 2 + (ks)][wr * 128 + m * 16 + fr][pgo];
#define LDB(bufi, ks, qn)                                                                  \
  bF0 = *(const bf16x8*)&Bs[(bufi) * 2 + (ks)][wc * 64 + (qn) * 32 + fr][pgo];             \
  bF1 = *(const bf16x8*)&Bs[(bufi) * 2 + (ks)][wc * 64 + (qn) * 32 + 16 + fr][pgo];
#define MM(qn)                                                                             \
  {                                                                                        \
    __builtin_amdgcn_s_setprio(1);                                                         \
    _Pragma("unroll") for (int m = 0; m < 8; ++m) {                                        \
      acc[m][(qn) * 2 + 0] =                                                               \
          __builtin_amdgcn_mfma_f32_16x16x32_bf16(aF[m], bF0, acc[m][(qn) * 2 + 0], 0, 0, 0); \
      acc[m][(qn) * 2 + 1] =                                                               \
          __builtin_amdgcn_mfma_f32_16x16x32_bf16(aF[m], bF1, acc[m][(qn) * 2 + 1], 0, 0, 0); \
    }                                                                                      \
    __builtin_amdgcn_s_setprio(0);                                                         \
  }
#define BARM() asm volatile("s_barrier" ::: "memory")
#define VMW(N) asm volatile("s_waitcnt vmcnt(" #N ")" ::: "memory")

  // prologue: tile0 (buf0) fully + tile1 (buf1) Kh0; retire tile0-Kh0 before P1
  STG_A(0, 0, 0); STG_B(0, 0, 0);
  STG_A(0, 1, 0); STG_B(0, 1, 0);
  STG_A(1, 0, 1); STG_B(1, 0, 1);
  VMW(8);
  BARM();

  for (int i = 0; i < 8; ++i) {
    const int t1s = 2 * i + 1, u0 = 2 * i + 2, u1 = 2 * i + 3;
    const bool st = (i < 7);
    // P1: compute buf0,ks0,qn0 ; stage A-Kh1(tile t1s -> buf1)
    LDA(0, 0); LDB(0, 0, 0); STG_A(1, 1, t1s);
    BARM(); MM(0); BARM();
    // P2
    LDB(0, 0, 1); STG_B(1, 1, t1s);
    BARM(); MM(1); VMW(8); BARM();
    // P3
    LDA(0, 1); LDB(0, 1, 0); if (st) STG_A(0, 0, u0);
    BARM(); MM(0); BARM();
    // P4
    LDB(0, 1, 1); if (st) STG_B(0, 0, u0);
    BARM(); MM(1);
    if (st) { VMW(8); } else { VMW(4); }
    BARM();
    // P5
    LDA(1, 0); LDB(1, 0, 0); if (st) STG_A(0, 1, u0);
    BARM(); MM(0); BARM();
    // P6
    LDB(1, 0, 1); if (st) STG_B(0, 1, u0);
    BARM(); MM(1);
    if (st) { VMW(8); } else { VMW(0); }
    BARM();
    // P7
    LDA(1, 1); LDB(1, 1, 0); if (st) STG_A(1, 0, u1);
    BARM(); MM(0); BARM();
    // P8
    LDB(1, 1, 1); if (st) STG_B(1, 0, u1);
    BARM(); MM(1); VMW(8); BARM();
  }
#undef STG_A
#undef STG_B
#undef LDA
#undef LDB
#undef MM
#undef BARM
#undef VMW

  if (NORM) {
    float bsv[4];
#pragma unroll
    for (int n = 0; n < 4; ++n) bsv[n] = bias[bn * 256 + wc * 64 + n * 16 + fr];
#pragma unroll
    for (int m = 0; m < 8; ++m) {
      float val[4][4];  // [n][j]
      float inv[4];
#pragma unroll
      for (int j = 0; j < 4; ++j) {
        float s = 0.f;
#pragma unroll
        for (int n = 0; n < 4; ++n) {
          val[n][j] = acc[m][n][j] + bsv[n];
          s += val[n][j] * val[n][j];
        }
        s += __shfl_xor(s, 1); s += __shfl_xor(s, 2);
        s += __shfl_xor(s, 4); s += __shfl_xor(s, 8);
        inv[j] = 1.f / fmaxf(sqrtf(s), 1e-12f);
      }
#pragma unroll
      for (int n = 0; n < 4; ++n) {
        const int col = bn * 256 + wc * 64 + n * 16 + fr;
#pragma unroll
        for (int j = 0; j < 4; ++j) {
          const int row = bm * 256 + wr * 128 + m * 16 + g4 + j;
          ((unsigned short*)C)[(size_t)row * 1024 + col] = f2bf(val[n][j] * inv[j]);
        }
      }
    }
  } else {
#pragma unroll
    for (int n = 0; n < 4; ++n) {
      const int col = bn * 256 + wc * 64 + n * 16 + fr;
      const float bsv = bias[col];
#pragma unroll
      for (int m = 0; m < 8; ++m) {
#pragma unroll
        for (int j = 0; j < 4; ++j) {
          const int row = bm * 256 + wr * 128 + m * 16 + g4 + j;
          ((float*)C)[(size_t)row * 1024 + col] = acc[m][n][j] + bsv;
        }
      }
    }
  }
}

// ---------------- proj pair: kh = norm(k@Wk^T+bk), vh = norm(v@Wv^T+bv) ----------------
__global__ __launch_bounds__(512, 1) void proj_norm_kernel(
    const unsigned short* __restrict__ A0, const unsigned short* __restrict__ A1,
    const unsigned short* __restrict__ B0, const unsigned short* __restrict__ B1,
    const float* __restrict__ bias0, const float* __restrict__ bias1,
    unsigned short* __restrict__ C0, unsigned short* __restrict__ C1) {
  __shared__ unsigned short As[4][256][32];
  __shared__ unsigned short Bs[4][256][32];
  const int flat = (blockIdx.z * 64 + blockIdx.y) * 4 + blockIdx.x;  // 512, %8==0
  const int swz = (flat & 7) * 64 + (flat >> 3);                     // bijective
  const int zz = swz >> 8;
  const int rem = swz & 255;
  const int bm = rem >> 2, bn = rem & 3;
  gemm256_body<true>(zz ? A1 : A0, zz ? B1 : B0, zz ? bias1 : bias0,
                     zz ? (void*)C1 : (void*)C0, bm, bn, As, Bs);
}

// ---------------- final: out = q_bf @ Beff_b^T + beff_b (f32 out) ----------------
__global__ __launch_bounds__(512, 1) void final_gemm_kernel(
    const unsigned short* __restrict__ A,     // q_bf [16384][1024]
    const unsigned short* __restrict__ Beff,  // [4][1024][1024] bf16
    const float* __restrict__ beff,           // [4][1024]
    float* __restrict__ out) {
  __shared__ unsigned short As[4][256][32];
  __shared__ unsigned short Bs[4][256][32];
  const int flat = blockIdx.y * 4 + blockIdx.x;  // 256, %8==0
  const int swz = (flat & 7) * 32 + (flat >> 3);
  const int bm = swz >> 2, bn = swz & 3;
  const int b = bm >> 4;  // 16 row-tiles of 256 per batch
  gemm256_body<false>(A, Beff + (size_t)b * 1048576, beff + b * 1024, out, bm, bn, As, Bs);
}

// ============ kv partials: kvp[chunk][b*16+h][i][j] = sum_{s in chunk} kh[s][i]*vh[s][j] ============
__global__ __launch_bounds__(256) void kv_part_kernel(const unsigned short* __restrict__ kh,
                                                      const unsigned short* __restrict__ vh,
                                                      float* __restrict__ kvp) {
  const int chunk = blockIdx.x, h = blockIdx.y, b = blockIdx.z;
  __shared__ unsigned short khT[64][264];
  __shared__ unsigned short vhT[64][264];
  const int tid = threadIdx.x, wid = tid >> 6, lane = tid & 63;
  const int fr = lane & 15, fk = (lane >> 4) * 8, g4 = (lane >> 4) * 4;

  const int jb = tid & 7, sb = tid >> 3;
  const size_t base = ((size_t)b * 4096 + chunk * 256) * 1024 + h * 64;
  {
    ushort8 rk[8], rv[8];
#pragma unroll
    for (int u = 0; u < 8; ++u) {
      rk[u] = *(const ushort8*)(kh + base + (size_t)(sb * 8 + u) * 1024 + jb * 8);
      rv[u] = *(const ushort8*)(vh + base + (size_t)(sb * 8 + u) * 1024 + jb * 8);
    }
#pragma unroll
    for (int jj = 0; jj < 8; ++jj) {
      ushort8 ck, cv;
#pragma unroll
      for (int u = 0; u < 8; ++u) { ck[u] = rk[u][jj]; cv[u] = rv[u][jj]; }
      *(ushort8*)&khT[jb * 8 + jj][sb * 8] = ck;
      *(ushort8*)&vhT[jb * 8 + jj][sb * 8] = cv;
    }
  }
  __syncthreads();

  f32x4 acc2[4];
#pragma unroll
  for (int n = 0; n < 4; ++n) acc2[n] = (f32x4){0.f, 0.f, 0.f, 0.f};
#pragma unroll
  for (int ks = 0; ks < 8; ++ks) {
    bf16x8 a2 = *(const bf16x8*)&khT[wid * 16 + fr][ks * 32 + fk];
    bf16x8 b2[4];
#pragma unroll
    for (int jt = 0; jt < 4; ++jt) b2[jt] = *(const bf16x8*)&vhT[jt * 16 + fr][ks * 32 + fk];
#pragma unroll
    for (int jt = 0; jt < 4; ++jt)
      acc2[jt] = __builtin_amdgcn_mfma_f32_16x16x32_bf16(a2, b2[jt], acc2[jt], 0, 0, 0);
  }
  float* dst = kvp + ((size_t)chunk * 64 + b * 16 + h) * 4096;
#pragma unroll
  for (int jt = 0; jt < 4; ++jt)
#pragma unroll
    for (int jj = 0; jj < 4; ++jj)
      dst[(wid * 16 + g4 + jj) * 64 + jt * 16 + fr] = acc2[jt][jj];
}

// ============ weff (+fused chunk reduce): Beff[b][h*64+j][d] = sum_i Wq[h*64+i][d]*kv[b,h,i,j] ============
__global__ __launch_bounds__(256) void weff_kernel(
    const unsigned short* __restrict__ Wq,   // bf16 [1024][1024]
    const float* __restrict__ bq,            // [1024]
    const float* __restrict__ kvp,           // [16][64][64][64] f32 partials
    unsigned short* __restrict__ Beff,       // [4][1024][1024] bf16
    float* __restrict__ beff) {              // [4][1024]
  const int dt = blockIdx.x, h = blockIdx.y, b = blockIdx.z;
  __shared__ float kvS[64 * 64];
  __shared__ float WqF[64 * 128];
  const int tid = threadIdx.x;

  const float* kvsrc = kvp + (size_t)(b * 16 + h) * 4096;
  for (int e = tid; e < 4096; e += 256) {
    float s = 0.f;
#pragma unroll
    for (int c = 0; c < 16; ++c) s += kvsrc[(size_t)c * 64 * 4096 + e];
    kvS[e] = s;
  }
  {
    int i = tid >> 2, dseg = tid & 3;
    const unsigned short* src = Wq + (size_t)(h * 64 + i) * 1024 + dt * 128 + dseg * 32;
    float* dst = &WqF[i * 128 + dseg * 32];
#pragma unroll
    for (int w = 0; w < 4; ++w) {
      ushort8 vv = ((const ushort8*)src)[w];
#pragma unroll
      for (int u = 0; u < 8; ++u) dst[w * 8 + u] = bf2f(vv[u]);
    }
  }
  __syncthreads();

  const int tj = tid & 63, tg = tid >> 6;
  float o[32];
#pragma unroll
  for (int dd = 0; dd < 32; ++dd) o[dd] = 0.f;
  for (int i = 0; i < 64; ++i) {
    float kvv = kvS[i * 64 + tj];
    const float* wr = &WqF[i * 128 + tg * 32];
#pragma unroll
    for (int dd = 0; dd < 32; ++dd) o[dd] += wr[dd] * kvv;
  }
  unsigned short* dstB = Beff + ((size_t)(b * 1024 + h * 64 + tj)) * 1024 + dt * 128 + tg * 32;
#pragma unroll
  for (int w = 0; w < 4; ++w) {
    ushort8 ov;
#pragma unroll
    for (int u = 0; u < 8; ++u) ov[u] = f2bf(o[w * 8 + u]);
    ((ushort8*)dstB)[w] = ov;
  }
  if (tg == 0 && dt == 0) {
    float s = 0.f;
    for (int i = 0; i < 64; ++i) s += bq[h * 64 + i] * kvS[i * 64 + tj];
    beff[b * 1024 + h * 64 + tj] = s;
  }
}

extern "C" void kernel_launch(void* const* d_in, const int* in_sizes, int n_in,
                              void* d_out, int out_size, void* d_ws, size_t ws_size,
                              hipStream_t stream) {
  const float* q = (const float*)d_in[0];
  const float* k = (const float*)d_in[1];
  const float* v = (const float*)d_in[2];
  const float* Wq = (const float*)d_in[3];
  const float* bq = (const float*)d_in[4];
  const float* Wk = (const float*)d_in[5];
  const float* bk = (const float*)d_in[6];
  const float* Wv = (const float*)d_in[7];
  const float* bv = (const float*)d_in[8];
  float* out = (float*)d_out;

  const size_t NE = (size_t)16384 * 1024;
  const size_t MB = 1048576;

  char* ws = (char*)d_ws;
  unsigned short* S0 = (unsigned short*)(ws + 0 * MB);    // k_bf; later kvp (16MB) + Beff (8MB @ +16MB)
  unsigned short* S1 = (unsigned short*)(ws + 32 * MB);   // v_bf; later q_bf
  unsigned short* kh = (unsigned short*)(ws + 64 * MB);   // 32 MB
  unsigned short* vh = (unsigned short*)(ws + 96 * MB);   // 32 MB
  unsigned short* Wqb = (unsigned short*)(ws + 128 * MB); // 2 MB
  unsigned short* Wkb = (unsigned short*)(ws + 130 * MB); // 2 MB
  unsigned short* Wvb = (unsigned short*)(ws + 132 * MB); // 2 MB
  float* beff = (float*)(ws + 134 * MB);                  // 16 KB
  float* kvp = (float*)S0;                                // 16 MB (k_bf dead by then)
  unsigned short* Beff = (unsigned short*)(ws + 16 * MB); // 8 MB

  // 1) k,v and weights -> bf16
  cvt2_kernel<<<dim3(8192, 2), 256, 0, stream>>>(k, v, S0, S1, (int)(NE / 8));
  cvt3w_kernel<<<dim3(512, 3), 256, 0, stream>>>(Wq, Wk, Wv, Wqb, Wkb, Wvb, 131072);

  // 2) projections + bias + L2 norm (256^2 8-phase, counted vmcnt, XCD-swizzled)
  proj_norm_kernel<<<dim3(4, 64, 2), 512, 0, stream>>>(S0, S1, Wkb, Wvb, bk, bv, kh, vh);

  // 3) q -> bf16 (into v_bf slot, now dead)
  cvt_kernel<<<8192, 256, 0, stream>>>(q, S1, (int)(NE / 8));

  // 4) kv chunk partials (deterministic, into k_bf slot, now dead)
  kv_part_kernel<<<dim3(16, 16, 4), 256, 0, stream>>>(kh, vh, kvp);

  // 5) weff: fused chunk-reduce + Wq-fold -> Beff bf16, beff
  weff_kernel<<<dim3(8, 16, 4), 256, 0, stream>>>(Wqb, bq, kvp, Beff, beff);

  // 6) out = q_bf @ Beff^T + beff (f32 out, 8-phase)
  final_gemm_kernel<<<dim3(4, 64), 512, 0, stream>>>(S1, Beff, beff, out);
}

// Round 9
// 235.986 us; speedup vs baseline: 1.6086x; 1.0113x over previous
//
#include <hip/hip_runtime.h>
#include <hip/hip_bf16.h>
#include <stdint.h>

typedef __attribute__((ext_vector_type(8))) short bf16x8;
typedef __attribute__((ext_vector_type(4))) float f32x4;
typedef __attribute__((ext_vector_type(8))) unsigned short ushort8;

__device__ __forceinline__ float bf2f(unsigned short u) {
  union { unsigned int i; float f; } x; x.i = ((unsigned int)u) << 16; return x.f;
}
__device__ __forceinline__ unsigned short f2bf(float f) {
  union { __hip_bfloat16 h; unsigned short u; } x; x.h = __float2bfloat16(f); return x.u;
}

__device__ __forceinline__ void gload_lds16(const void* g, void* l) {
  __builtin_amdgcn_global_load_lds((__attribute__((address_space(1))) const void*)g,
                                   (__attribute__((address_space(3))) void*)l, 16, 0, 0);
}

// ---------------- f32 -> bf16 converts ----------------
__global__ __launch_bounds__(256) void cvt_kernel(const float* __restrict__ in,
                                                  unsigned short* __restrict__ out,
                                                  int n8) {
  int i = blockIdx.x * 256 + threadIdx.x;
  if (i >= n8) return;
  const float4* p = (const float4*)(in + (size_t)i * 8);
  float4 a = p[0], b = p[1];
  ushort8 o;
  o[0] = f2bf(a.x); o[1] = f2bf(a.y); o[2] = f2bf(a.z); o[3] = f2bf(a.w);
  o[4] = f2bf(b.x); o[5] = f2bf(b.y); o[6] = f2bf(b.z); o[7] = f2bf(b.w);
  *(ushort8*)(out + (size_t)i * 8) = o;
}

__global__ __launch_bounds__(256) void cvt2_kernel(const float* __restrict__ a,
                                                   const float* __restrict__ b,
                                                   unsigned short* __restrict__ oa,
                                                   unsigned short* __restrict__ ob,
                                                   int n8) {
  const float* in = blockIdx.y ? b : a;
  unsigned short* out = blockIdx.y ? ob : oa;
  int i = blockIdx.x * 256 + threadIdx.x;
  if (i >= n8) return;
  const float4* p = (const float4*)(in + (size_t)i * 8);
  float4 x = p[0], y = p[1];
  ushort8 o;
  o[0] = f2bf(x.x); o[1] = f2bf(x.y); o[2] = f2bf(x.z); o[3] = f2bf(x.w);
  o[4] = f2bf(y.x); o[5] = f2bf(y.y); o[6] = f2bf(y.z); o[7] = f2bf(y.w);
  *(ushort8*)(out + (size_t)i * 8) = o;
}

__global__ __launch_bounds__(256) void cvt3w_kernel(const float* __restrict__ a,
                                                    const float* __restrict__ b,
                                                    const float* __restrict__ c,
                                                    unsigned short* __restrict__ oa,
                                                    unsigned short* __restrict__ ob,
                                                    unsigned short* __restrict__ oc,
                                                    int n8) {
  const float* in = blockIdx.y == 0 ? a : blockIdx.y == 1 ? b : c;
  unsigned short* out = blockIdx.y == 0 ? oa : blockIdx.y == 1 ? ob : oc;
  int i = blockIdx.x * 256 + threadIdx.x;
  if (i >= n8) return;
  const float4* p = (const float4*)(in + (size_t)i * 8);
  float4 x = p[0], y = p[1];
  ushort8 o;
  o[0] = f2bf(x.x); o[1] = f2bf(x.y); o[2] = f2bf(x.z); o[3] = f2bf(x.w);
  o[4] = f2bf(y.x); o[5] = f2bf(y.y); o[6] = f2bf(y.z); o[7] = f2bf(y.w);
  *(ushort8*)(out + (size_t)i * 8) = o;
}

// ======================================================================
// 8-phase 256x256 GEMM body: C = A_bf16[M,1024] @ B_bf16[1024,1024]^T (+bias)
// BK=64 split in 2 K-halves of 32; LDS As/Bs[buf2][ks2][256][32] = 128 KB.
// 8 waves (2M x 4N), per-wave out 128x64. Phase:
//   {ds_read frags || stage 1 quarter-tile} -> barrier -> lgkmcnt(0) ->
//   16 MFMA (setprio) -> [counted vmcnt] -> barrier
// Swizzle key (r7-verified 0-conflict): phys granule = logical ^ ((row>>1)&3),
// applied to gload source (linear dest) and frag reads.
// ======================================================================
template <bool NORM>
__device__ __forceinline__ void gemm256_body(
    const unsigned short* __restrict__ A,
    const unsigned short* __restrict__ B,
    const float* __restrict__ bias,
    void* __restrict__ C,
    int bm, int bn,
    unsigned short (*As)[256][32],  // [4] = buf*2+ks
    unsigned short (*Bs)[256][32]) {
  const int tid = threadIdx.x;
  const int widx = tid >> 6, lane = tid & 63;
  const int wr = widx >> 2, wc = widx & 3;
  const int fr = lane & 15, fkg = lane >> 4;
  const int g4 = fkg * 4;
  const int pgo = (fkg ^ ((fr >> 1) & 3)) * 8;        // swizzled read granule (elems)
  const int srow = lane >> 2;                         // staging row-in-16
  const int sg = ((lane & 3) ^ ((lane >> 3) & 3)) * 8;  // swizzled source granule (elems)

  const size_t abase = (size_t)(bm * 256) * 1024;
  const size_t bbase = (size_t)(bn * 256) * 1024;

  f32x4 acc[8][4];
#pragma unroll
  for (int m = 0; m < 8; ++m)
#pragma unroll
    for (int n = 0; n < 4; ++n) acc[m][n] = (f32x4){0.f, 0.f, 0.f, 0.f};

  bf16x8 aF[8], bF0, bF1;

#define STG_A(bufi, kh, kt)                                                                \
  {                                                                                        \
    gload_lds16(A + abase + (size_t)(widx * 16 + srow) * 1024 + (kt) * 64 + (kh) * 32 + sg,\
                &As[(bufi) * 2 + (kh)][widx * 16][0]);                                     \
    gload_lds16(A + abase + (size_t)(128 + widx * 16 + srow) * 1024 + (kt) * 64 + (kh) * 32 + sg, \
                &As[(bufi) * 2 + (kh)][128 + widx * 16][0]);                               \
  }
#define STG_B(bufi, kh, kt)                                                                \
  {                                                                                        \
    gload_lds16(B + bbase + (size_t)(widx * 16 + srow) * 1024 + (kt) * 64 + (kh) * 32 + sg,\
                &Bs[(bufi) * 2 + (kh)][widx * 16][0]);                                     \
    gload_lds16(B + bbase + (size_t)(128 + widx * 16 + srow) * 1024 + (kt) * 64 + (kh) * 32 + sg, \
                &Bs[(bufi) * 2 + (kh)][128 + widx * 16][0]);                               \
  }
#define LDA(bufi, ks)                                                                      \
  _Pragma("unroll") for (int m = 0; m < 8; ++m)                                            \
      aF[m] = *(const bf16x8*)&As[(bufi) * 2 + (ks)][wr * 128 + m * 16 + fr][pgo];
#define LDB(bufi, ks, qn)                                                                  \
  bF0 = *(const bf16x8*)&Bs[(bufi) * 2 + (ks)][wc * 64 + (qn) * 32 + fr][pgo];             \
  bF1 = *(const bf16x8*)&Bs[(bufi) * 2 + (ks)][wc * 64 + (qn) * 32 + 16 + fr][pgo];
#define MM(qn)                                                                             \
  {                                                                                        \
    __builtin_amdgcn_s_setprio(1);                                                         \
    _Pragma("unroll") for (int m = 0; m < 8; ++m) {                                        \
      acc[m][(qn) * 2 + 0] =                                                               \
          __builtin_amdgcn_mfma_f32_16x16x32_bf16(aF[m], bF0, acc[m][(qn) * 2 + 0], 0, 0, 0); \
      acc[m][(qn) * 2 + 1] =                                                               \
          __builtin_amdgcn_mfma_f32_16x16x32_bf16(aF[m], bF1, acc[m][(qn) * 2 + 1], 0, 0, 0); \
    }                                                                                      \
    __builtin_amdgcn_s_setprio(0);                                                         \
  }
#define BARM() asm volatile("s_barrier" ::: "memory")
#define LGKM()                                          \
  asm volatile("s_waitcnt lgkmcnt(0)" ::: "memory");    \
  __builtin_amdgcn_sched_barrier(0)
#define VMW(N) asm volatile("s_waitcnt vmcnt(" #N ")" ::: "memory")

  // prologue: tile0 (buf0) fully + tile1 (buf1) Kh0; retire tile0 before P1
  STG_A(0, 0, 0); STG_B(0, 0, 0);
  STG_A(0, 1, 0); STG_B(0, 1, 0);
  STG_A(1, 0, 1); STG_B(1, 0, 1);
  VMW(8);
  BARM();

  for (int i = 0; i < 8; ++i) {
    const int t1s = 2 * i + 1, u0 = 2 * i + 2, u1 = 2 * i + 3;
    const bool st = (i < 7);
    // P1: compute buf0,ks0,qn0 ; stage A-Kh1(tile t1s -> buf1)
    LDA(0, 0); LDB(0, 0, 0); STG_A(1, 1, t1s);
    BARM(); LGKM(); MM(0); BARM();
    // P2
    LDB(0, 0, 1); STG_B(1, 1, t1s);
    BARM(); LGKM(); MM(1); VMW(8); BARM();
    // P3
    LDA(0, 1); LDB(0, 1, 0); if (st) STG_A(0, 0, u0);
    BARM(); LGKM(); MM(0); BARM();
    // P4
    LDB(0, 1, 1); if (st) STG_B(0, 0, u0);
    BARM(); LGKM(); MM(1);
    if (st) { VMW(8); } else { VMW(4); }
    BARM();
    // P5
    LDA(1, 0); LDB(1, 0, 0); if (st) STG_A(0, 1, u0);
    BARM(); LGKM(); MM(0); BARM();
    // P6
    LDB(1, 0, 1); if (st) STG_B(0, 1, u0);
    BARM(); LGKM(); MM(1);
    if (st) { VMW(8); } else { VMW(0); }
    BARM();
    // P7
    LDA(1, 1); LDB(1, 1, 0); if (st) STG_A(1, 0, u1);
    BARM(); LGKM(); MM(0); BARM();
    // P8
    LDB(1, 1, 1); if (st) STG_B(1, 0, u1);
    BARM(); LGKM(); MM(1); VMW(8); BARM();
  }
#undef STG_A
#undef STG_B
#undef LDA
#undef LDB
#undef MM
#undef BARM
#undef LGKM
#undef VMW

  if (NORM) {
    float bsv[4];
#pragma unroll
    for (int n = 0; n < 4; ++n) bsv[n] = bias[bn * 256 + wc * 64 + n * 16 + fr];
#pragma unroll
    for (int m = 0; m < 8; ++m) {
      float val[4][4];  // [n][j]
      float inv[4];
#pragma unroll
      for (int j = 0; j < 4; ++j) {
        float s = 0.f;
#pragma unroll
        for (int n = 0; n < 4; ++n) {
          val[n][j] = acc[m][n][j] + bsv[n];
          s += val[n][j] * val[n][j];
        }
        s += __shfl_xor(s, 1); s += __shfl_xor(s, 2);
        s += __shfl_xor(s, 4); s += __shfl_xor(s, 8);
        inv[j] = 1.f / fmaxf(sqrtf(s), 1e-12f);
      }
#pragma unroll
      for (int n = 0; n < 4; ++n) {
        const int col = bn * 256 + wc * 64 + n * 16 + fr;
#pragma unroll
        for (int j = 0; j < 4; ++j) {
          const int row = bm * 256 + wr * 128 + m * 16 + g4 + j;
          ((unsigned short*)C)[(size_t)row * 1024 + col] = f2bf(val[n][j] * inv[j]);
        }
      }
    }
  } else {
#pragma unroll
    for (int n = 0; n < 4; ++n) {
      const int col = bn * 256 + wc * 64 + n * 16 + fr;
      const float bsv = bias[col];
#pragma unroll
      for (int m = 0; m < 8; ++m) {
#pragma unroll
        for (int j = 0; j < 4; ++j) {
          const int row = bm * 256 + wr * 128 + m * 16 + g4 + j;
          ((float*)C)[(size_t)row * 1024 + col] = acc[m][n][j] + bsv;
        }
      }
    }
  }
}

// ---------------- proj pair: kh = norm(k@Wk^T+bk), vh = norm(v@Wv^T+bv) ----------------
__global__ __launch_bounds__(512, 1) void proj_norm_kernel(
    const unsigned short* __restrict__ A0, const unsigned short* __restrict__ A1,
    const unsigned short* __restrict__ B0, const unsigned short* __restrict__ B1,
    const float* __restrict__ bias0, const float* __restrict__ bias1,
    unsigned short* __restrict__ C0, unsigned short* __restrict__ C1) {
  __shared__ unsigned short As[4][256][32];
  __shared__ unsigned short Bs[4][256][32];
  const int flat = (blockIdx.z * 64 + blockIdx.y) * 4 + blockIdx.x;  // 512, %8==0
  const int swz = (flat & 7) * 64 + (flat >> 3);                     // bijective
  const int zz = swz >> 8;
  const int rem = swz & 255;
  const int bm = rem >> 2, bn = rem & 3;
  gemm256_body<true>(zz ? A1 : A0, zz ? B1 : B0, zz ? bias1 : bias0,
                     zz ? (void*)C1 : (void*)C0, bm, bn, As, Bs);
}

// ---------------- final: out = q_bf @ Beff_b^T + beff_b (f32 out) ----------------
__global__ __launch_bounds__(512, 1) void final_gemm_kernel(
    const unsigned short* __restrict__ A,     // q_bf [16384][1024]
    const unsigned short* __restrict__ Beff,  // [4][1024][1024] bf16
    const float* __restrict__ beff,           // [4][1024]
    float* __restrict__ out) {
  __shared__ unsigned short As[4][256][32];
  __shared__ unsigned short Bs[4][256][32];
  const int flat = blockIdx.y * 4 + blockIdx.x;  // 256, %8==0
  const int swz = (flat & 7) * 32 + (flat >> 3);
  const int bm = swz >> 2, bn = swz & 3;
  const int b = bm >> 4;  // 16 row-tiles of 256 per batch
  gemm256_body<false>(A, Beff + (size_t)b * 1048576, beff + b * 1024, out, bm, bn, As, Bs);
}

// ============ kv partials: kvp[chunk][b*16+h][i][j] = sum_{s in chunk} kh[s][i]*vh[s][j] ============
__global__ __launch_bounds__(256) void kv_part_kernel(const unsigned short* __restrict__ kh,
                                                      const unsigned short* __restrict__ vh,
                                                      float* __restrict__ kvp) {
  const int chunk = blockIdx.x, h = blockIdx.y, b = blockIdx.z;
  __shared__ unsigned short khT[64][264];
  __shared__ unsigned short vhT[64][264];
  const int tid = threadIdx.x, wid = tid >> 6, lane = tid & 63;
  const int fr = lane & 15, fk = (lane >> 4) * 8, g4 = (lane >> 4) * 4;

  const int jb = tid & 7, sb = tid >> 3;
  const size_t base = ((size_t)b * 4096 + chunk * 256) * 1024 + h * 64;
  {
    ushort8 rk[8], rv[8];
#pragma unroll
    for (int u = 0; u < 8; ++u) {
      rk[u] = *(const ushort8*)(kh + base + (size_t)(sb * 8 + u) * 1024 + jb * 8);
      rv[u] = *(const ushort8*)(vh + base + (size_t)(sb * 8 + u) * 1024 + jb * 8);
    }
#pragma unroll
    for (int jj = 0; jj < 8; ++jj) {
      ushort8 ck, cv;
#pragma unroll
      for (int u = 0; u < 8; ++u) { ck[u] = rk[u][jj]; cv[u] = rv[u][jj]; }
      *(ushort8*)&khT[jb * 8 + jj][sb * 8] = ck;
      *(ushort8*)&vhT[jb * 8 + jj][sb * 8] = cv;
    }
  }
  __syncthreads();

  f32x4 acc2[4];
#pragma unroll
  for (int n = 0; n < 4; ++n) acc2[n] = (f32x4){0.f, 0.f, 0.f, 0.f};
#pragma unroll
  for (int ks = 0; ks < 8; ++ks) {
    bf16x8 a2 = *(const bf16x8*)&khT[wid * 16 + fr][ks * 32 + fk];
    bf16x8 b2[4];
#pragma unroll
    for (int jt = 0; jt < 4; ++jt) b2[jt] = *(const bf16x8*)&vhT[jt * 16 + fr][ks * 32 + fk];
#pragma unroll
    for (int jt = 0; jt < 4; ++jt)
      acc2[jt] = __builtin_amdgcn_mfma_f32_16x16x32_bf16(a2, b2[jt], acc2[jt], 0, 0, 0);
  }
  float* dst = kvp + ((size_t)chunk * 64 + b * 16 + h) * 4096;
#pragma unroll
  for (int jt = 0; jt < 4; ++jt)
#pragma unroll
    for (int jj = 0; jj < 4; ++jj)
      dst[(wid * 16 + g4 + jj) * 64 + jt * 16 + fr] = acc2[jt][jj];
}

// ============ weff (+fused chunk reduce): Beff[b][h*64+j][d] = sum_i Wq[h*64+i][d]*kv[b,h,i,j] ============
__global__ __launch_bounds__(256) void weff_kernel(
    const unsigned short* __restrict__ Wq,   // bf16 [1024][1024]
    const float* __restrict__ bq,            // [1024]
    const float* __restrict__ kvp,           // [16][64][64][64] f32 partials
    unsigned short* __restrict__ Beff,       // [4][1024][1024] bf16
    float* __restrict__ beff) {              // [4][1024]
  const int dt = blockIdx.x, h = blockIdx.y, b = blockIdx.z;
  __shared__ float kvS[64 * 64];
  __shared__ float WqF[64 * 128];
  const int tid = threadIdx.x;

  const float* kvsrc = kvp + (size_t)(b * 16 + h) * 4096;
  for (int e = tid; e < 4096; e += 256) {
    float s = 0.f;
#pragma unroll
    for (int c = 0; c < 16; ++c) s += kvsrc[(size_t)c * 64 * 4096 + e];
    kvS[e] = s;
  }
  {
    int i = tid >> 2, dseg = tid & 3;
    const unsigned short* src = Wq + (size_t)(h * 64 + i) * 1024 + dt * 128 + dseg * 32;
    float* dst = &WqF[i * 128 + dseg * 32];
#pragma unroll
    for (int w = 0; w < 4; ++w) {
      ushort8 vv = ((const ushort8*)src)[w];
#pragma unroll
      for (int u = 0; u < 8; ++u) dst[w * 8 + u] = bf2f(vv[u]);
    }
  }
  __syncthreads();

  const int tj = tid & 63, tg = tid >> 6;
  float o[32];
#pragma unroll
  for (int dd = 0; dd < 32; ++dd) o[dd] = 0.f;
  for (int i = 0; i < 64; ++i) {
    float kvv = kvS[i * 64 + tj];
    const float* wr = &WqF[i * 128 + tg * 32];
#pragma unroll
    for (int dd = 0; dd < 32; ++dd) o[dd] += wr[dd] * kvv;
  }
  unsigned short* dstB = Beff + ((size_t)(b * 1024 + h * 64 + tj)) * 1024 + dt * 128 + tg * 32;
#pragma unroll
  for (int w = 0; w < 4; ++w) {
    ushort8 ov;
#pragma unroll
    for (int u = 0; u < 8; ++u) ov[u] = f2bf(o[w * 8 + u]);
    ((ushort8*)dstB)[w] = ov;
  }
  if (tg == 0 && dt == 0) {
    float s = 0.f;
    for (int i = 0; i < 64; ++i) s += bq[h * 64 + i] * kvS[i * 64 + tj];
    beff[b * 1024 + h * 64 + tj] = s;
  }
}

extern "C" void kernel_launch(void* const* d_in, const int* in_sizes, int n_in,
                              void* d_out, int out_size, void* d_ws, size_t ws_size,
                              hipStream_t stream) {
  const float* q = (const float*)d_in[0];
  const float* k = (const float*)d_in[1];
  const float* v = (const float*)d_in[2];
  const float* Wq = (const float*)d_in[3];
  const float* bq = (const float*)d_in[4];
  const float* Wk = (const float*)d_in[5];
  const float* bk = (const float*)d_in[6];
  const float* Wv = (const float*)d_in[7];
  const float* bv = (const float*)d_in[8];
  float* out = (float*)d_out;

  const size_t NE = (size_t)16384 * 1024;
  const size_t MB = 1048576;

  char* ws = (char*)d_ws;
  unsigned short* S0 = (unsigned short*)(ws + 0 * MB);    // k_bf; later kvp (16MB) + Beff (8MB @ +16MB)
  unsigned short* S1 = (unsigned short*)(ws + 32 * MB);   // v_bf; later q_bf
  unsigned short* kh = (unsigned short*)(ws + 64 * MB);   // 32 MB
  unsigned short* vh = (unsigned short*)(ws + 96 * MB);   // 32 MB
  unsigned short* Wqb = (unsigned short*)(ws + 128 * MB); // 2 MB
  unsigned short* Wkb = (unsigned short*)(ws + 130 * MB); // 2 MB
  unsigned short* Wvb = (unsigned short*)(ws + 132 * MB); // 2 MB
  float* beff = (float*)(ws + 134 * MB);                  // 16 KB
  float* kvp = (float*)S0;                                // 16 MB (k_bf dead by then)
  unsigned short* Beff = (unsigned short*)(ws + 16 * MB); // 8 MB

  // 1) k,v and weights -> bf16
  cvt2_kernel<<<dim3(8192, 2), 256, 0, stream>>>(k, v, S0, S1, (int)(NE / 8));
  cvt3w_kernel<<<dim3(512, 3), 256, 0, stream>>>(Wq, Wk, Wv, Wqb, Wkb, Wvb, 131072);

  // 2) projections + bias + L2 norm (256^2 8-phase, counted vmcnt, XCD-swizzled)
  proj_norm_kernel<<<dim3(4, 64, 2), 512, 0, stream>>>(S0, S1, Wkb, Wvb, bk, bv, kh, vh);

  // 3) q -> bf16 (into v_bf slot, now dead)
  cvt_kernel<<<8192, 256, 0, stream>>>(q, S1, (int)(NE / 8));

  // 4) kv chunk partials (deterministic, into k_bf slot, now dead)
  kv_part_kernel<<<dim3(16, 16, 4), 256, 0, stream>>>(kh, vh, kvp);

  // 5) weff: fused chunk-reduce + Wq-fold -> Beff bf16, beff
  weff_kernel<<<dim3(8, 16, 4), 256, 0, stream>>>(Wqb, bq, kvp, Beff, beff);

  // 6) out = q_bf @ Beff^T + beff (f32 out, 8-phase)
  final_gemm_kernel<<<dim3(4, 64), 512, 0, stream>>>(S1, Beff, beff, out);
}

// Round 10
// 232.876 us; speedup vs baseline: 1.6301x; 1.0134x over previous
//
#include <hip/hip_runtime.h>
#include <hip/hip_bf16.h>
#include <stdint.h>

typedef __attribute__((ext_vector_type(8))) short bf16x8;
typedef __attribute__((ext_vector_type(4))) float f32x4;
typedef __attribute__((ext_vector_type(8))) unsigned short ushort8;

__device__ __forceinline__ float bf2f(unsigned short u) {
  union { unsigned int i; float f; } x; x.i = ((unsigned int)u) << 16; return x.f;
}
__device__ __forceinline__ unsigned short f2bf(float f) {
  union { __hip_bfloat16 h; unsigned short u; } x; x.h = __float2bfloat16(f); return x.u;
}

__device__ __forceinline__ void gload_lds16(const void* g, void* l) {
  __builtin_amdgcn_global_load_lds((__attribute__((address_space(1))) const void*)g,
                                   (__attribute__((address_space(3))) void*)l, 16, 0, 0);
}

// ---------------- f32 -> bf16 converts ----------------
__global__ __launch_bounds__(256) void cvt_kernel(const float* __restrict__ in,
                                                  unsigned short* __restrict__ out,
                                                  int n8) {
  int i = blockIdx.x * 256 + threadIdx.x;
  if (i >= n8) return;
  const float4* p = (const float4*)(in + (size_t)i * 8);
  float4 a = p[0], b = p[1];
  ushort8 o;
  o[0] = f2bf(a.x); o[1] = f2bf(a.y); o[2] = f2bf(a.z); o[3] = f2bf(a.w);
  o[4] = f2bf(b.x); o[5] = f2bf(b.y); o[6] = f2bf(b.z); o[7] = f2bf(b.w);
  *(ushort8*)(out + (size_t)i * 8) = o;
}

__global__ __launch_bounds__(256) void cvt2_kernel(const float* __restrict__ a,
                                                   const float* __restrict__ b,
                                                   unsigned short* __restrict__ oa,
                                                   unsigned short* __restrict__ ob,
                                                   int n8) {
  const float* in = blockIdx.y ? b : a;
  unsigned short* out = blockIdx.y ? ob : oa;
  int i = blockIdx.x * 256 + threadIdx.x;
  if (i >= n8) return;
  const float4* p = (const float4*)(in + (size_t)i * 8);
  float4 x = p[0], y = p[1];
  ushort8 o;
  o[0] = f2bf(x.x); o[1] = f2bf(x.y); o[2] = f2bf(x.z); o[3] = f2bf(x.w);
  o[4] = f2bf(y.x); o[5] = f2bf(y.y); o[6] = f2bf(y.z); o[7] = f2bf(y.w);
  *(ushort8*)(out + (size_t)i * 8) = o;
}

__global__ __launch_bounds__(256) void cvt3w_kernel(const float* __restrict__ a,
                                                    const float* __restrict__ b,
                                                    const float* __restrict__ c,
                                                    unsigned short* __restrict__ oa,
                                                    unsigned short* __restrict__ ob,
                                                    unsigned short* __restrict__ oc,
                                                    int n8) {
  const float* in = blockIdx.y == 0 ? a : blockIdx.y == 1 ? b : c;
  unsigned short* out = blockIdx.y == 0 ? oa : blockIdx.y == 1 ? ob : oc;
  int i = blockIdx.x * 256 + threadIdx.x;
  if (i >= n8) return;
  const float4* p = (const float4*)(in + (size_t)i * 8);
  float4 x = p[0], y = p[1];
  ushort8 o;
  o[0] = f2bf(x.x); o[1] = f2bf(x.y); o[2] = f2bf(x.z); o[3] = f2bf(x.w);
  o[4] = f2bf(y.x); o[5] = f2bf(y.y); o[6] = f2bf(y.z); o[7] = f2bf(y.w);
  *(ushort8*)(out + (size_t)i * 8) = o;
}

// ======================================================================
// 4-phase 256x256 GEMM body: C = A_bf16[M,1024] @ B_bf16[1024,1024]^T (+bias)
// BK=64 split in 2 K-halves of 32; LDS As/Bs[buf2][ks2][256][32] = 128 KB.
// 8 waves (2M x 4N), per-wave out 128x64. One phase per (buf,ks):
//   {LDA 8 + LDB 4 ds_read_b128 || stage A+B K-half unit} -> barrier ->
//   lgkmcnt(0) -> 32 MFMA (setprio) -> counted vmcnt(8) -> barrier
// Swizzle (0-conflict verified r7/r9): phys granule = logical ^ ((row>>1)&3),
// on gload SOURCE (linear dest) and frag reads.
// ======================================================================
template <bool NORM>
__device__ __forceinline__ void gemm256_body(
    const unsigned short* __restrict__ A,
    const unsigned short* __restrict__ B,
    const float* __restrict__ bias,
    void* __restrict__ C,
    int bm, int bn,
    unsigned short (*As)[256][32],  // [4] = buf*2+ks
    unsigned short (*Bs)[256][32]) {
  const int tid = threadIdx.x;
  const int widx = tid >> 6, lane = tid & 63;
  const int wr = widx >> 2, wc = widx & 3;
  const int fr = lane & 15, fkg = lane >> 4;
  const int g4 = fkg * 4;
  const int pgo = (fkg ^ ((fr >> 1) & 3)) * 8;          // swizzled read granule (elems)
  const int srow = lane >> 2;                           // staging row-in-16
  const int sg = ((lane & 3) ^ ((lane >> 3) & 3)) * 8;  // swizzled source granule (elems)

  const size_t abase = (size_t)(bm * 256) * 1024;
  const size_t bbase = (size_t)(bn * 256) * 1024;

  f32x4 acc[8][4];
#pragma unroll
  for (int m = 0; m < 8; ++m)
#pragma unroll
    for (int n = 0; n < 4; ++n) acc[m][n] = (f32x4){0.f, 0.f, 0.f, 0.f};

  bf16x8 aF[8], bF[4];

#define STG_A(bufi, kh, kt)                                                                \
  {                                                                                        \
    gload_lds16(A + abase + (size_t)(widx * 16 + srow) * 1024 + (kt) * 64 + (kh) * 32 + sg,\
                &As[(bufi) * 2 + (kh)][widx * 16][0]);                                     \
    gload_lds16(A + abase + (size_t)(128 + widx * 16 + srow) * 1024 + (kt) * 64 + (kh) * 32 + sg, \
                &As[(bufi) * 2 + (kh)][128 + widx * 16][0]);                               \
  }
#define STG_B(bufi, kh, kt)                                                                \
  {                                                                                        \
    gload_lds16(B + bbase + (size_t)(widx * 16 + srow) * 1024 + (kt) * 64 + (kh) * 32 + sg,\
                &Bs[(bufi) * 2 + (kh)][widx * 16][0]);                                     \
    gload_lds16(B + bbase + (size_t)(128 + widx * 16 + srow) * 1024 + (kt) * 64 + (kh) * 32 + sg, \
                &Bs[(bufi) * 2 + (kh)][128 + widx * 16][0]);                               \
  }
#define LDA(bufi, ks)                                                                      \
  _Pragma("unroll") for (int m = 0; m < 8; ++m)                                            \
      aF[m] = *(const bf16x8*)&As[(bufi) * 2 + (ks)][wr * 128 + m * 16 + fr][pgo];
#define LDBALL(bufi, ks)                                                                   \
  _Pragma("unroll") for (int n = 0; n < 4; ++n)                                            \
      bF[n] = *(const bf16x8*)&Bs[(bufi) * 2 + (ks)][wc * 64 + n * 16 + fr][pgo];
#define MMALL()                                                                            \
  {                                                                                        \
    __builtin_amdgcn_s_setprio(1);                                                         \
    _Pragma("unroll") for (int m = 0; m < 8; ++m)                                          \
        _Pragma("unroll") for (int n = 0; n < 4; ++n)                                      \
            acc[m][n] = __builtin_amdgcn_mfma_f32_16x16x32_bf16(aF[m], bF[n], acc[m][n], 0, 0, 0); \
    __builtin_amdgcn_s_setprio(0);                                                         \
  }
#define BARM() asm volatile("s_barrier" ::: "memory")
#define LGKM()                                          \
  asm volatile("s_waitcnt lgkmcnt(0)" ::: "memory");    \
  __builtin_amdgcn_sched_barrier(0)
#define VMW(N) asm volatile("s_waitcnt vmcnt(" #N ")" ::: "memory")

  // prologue: tile0 both K-halves + tile1 Kh0; retire tile0 before P1
  STG_A(0, 0, 0); STG_B(0, 0, 0);
  STG_A(0, 1, 0); STG_B(0, 1, 0);
  STG_A(1, 0, 1); STG_B(1, 0, 1);
  VMW(4);
  BARM();

  for (int i = 0; i < 8; ++i) {
    const int t1s = 2 * i + 1, u0 = 2 * i + 2, u1 = 2 * i + 3;
    const bool st = (i < 7);
    // P1: compute (buf0,ks0); stage (buf1,ks1) <- tile t1s
    LDA(0, 0); LDBALL(0, 0); STG_A(1, 1, t1s); STG_B(1, 1, t1s);
    BARM(); LGKM(); MMALL(); VMW(8); BARM();
    // P2: compute (buf0,ks1); stage (buf0,ks0) <- tile u0
    LDA(0, 1); LDBALL(0, 1); if (st) { STG_A(0, 0, u0); STG_B(0, 0, u0); }
    BARM(); LGKM(); MMALL(); VMW(8); BARM();
    // P3: compute (buf1,ks0); stage (buf0,ks1) <- tile u0
    LDA(1, 0); LDBALL(1, 0); if (st) { STG_A(0, 1, u0); STG_B(0, 1, u0); }
    BARM(); LGKM(); MMALL();
    if (st) { VMW(8); } else { VMW(0); }
    BARM();
    // P4: compute (buf1,ks1); stage (buf1,ks0) <- tile u1
    LDA(1, 1); LDBALL(1, 1); if (st) { STG_A(1, 0, u1); STG_B(1, 0, u1); }
    BARM(); LGKM(); MMALL();
    if (st) { VMW(8); } else { VMW(0); }
    BARM();
  }
#undef STG_A
#undef STG_B
#undef LDA
#undef LDBALL
#undef MMALL
#undef BARM
#undef LGKM
#undef VMW

  if (NORM) {
    float bsv[4];
#pragma unroll
    for (int n = 0; n < 4; ++n) bsv[n] = bias[bn * 256 + wc * 64 + n * 16 + fr];
#pragma unroll
    for (int m = 0; m < 8; ++m) {
      float val[4][4];  // [n][j]
      float inv[4];
#pragma unroll
      for (int j = 0; j < 4; ++j) {
        float s = 0.f;
#pragma unroll
        for (int n = 0; n < 4; ++n) {
          val[n][j] = acc[m][n][j] + bsv[n];
          s += val[n][j] * val[n][j];
        }
        s += __shfl_xor(s, 1); s += __shfl_xor(s, 2);
        s += __shfl_xor(s, 4); s += __shfl_xor(s, 8);
        inv[j] = 1.f / fmaxf(sqrtf(s), 1e-12f);
      }
#pragma unroll
      for (int n = 0; n < 4; ++n) {
        const int col = bn * 256 + wc * 64 + n * 16 + fr;
#pragma unroll
        for (int j = 0; j < 4; ++j) {
          const int row = bm * 256 + wr * 128 + m * 16 + g4 + j;
          ((unsigned short*)C)[(size_t)row * 1024 + col] = f2bf(val[n][j] * inv[j]);
        }
      }
    }
  } else {
#pragma unroll
    for (int n = 0; n < 4; ++n) {
      const int col = bn * 256 + wc * 64 + n * 16 + fr;
      const float bsv = bias[col];
#pragma unroll
      for (int m = 0; m < 8; ++m) {
#pragma unroll
        for (int j = 0; j < 4; ++j) {
          const int row = bm * 256 + wr * 128 + m * 16 + g4 + j;
          ((float*)C)[(size_t)row * 1024 + col] = acc[m][n][j] + bsv;
        }
      }
    }
  }
}

// ---------------- proj pair: kh = norm(k@Wk^T+bk), vh = norm(v@Wv^T+bv) ----------------
__global__ __launch_bounds__(512, 1) void proj_norm_kernel(
    const unsigned short* __restrict__ A0, const unsigned short* __restrict__ A1,
    const unsigned short* __restrict__ B0, const unsigned short* __restrict__ B1,
    const float* __restrict__ bias0, const float* __restrict__ bias1,
    unsigned short* __restrict__ C0, unsigned short* __restrict__ C1) {
  __shared__ unsigned short As[4][256][32];
  __shared__ unsigned short Bs[4][256][32];
  const int flat = (blockIdx.z * 64 + blockIdx.y) * 4 + blockIdx.x;  // 512, %8==0
  const int swz = (flat & 7) * 64 + (flat >> 3);                     // bijective
  const int zz = swz >> 8;
  const int rem = swz & 255;
  const int bm = rem >> 2, bn = rem & 3;
  gemm256_body<true>(zz ? A1 : A0, zz ? B1 : B0, zz ? bias1 : bias0,
                     zz ? (void*)C1 : (void*)C0, bm, bn, As, Bs);
}

// ---------------- final: out = q_bf @ Beff_b^T + beff_b (f32 out) ----------------
__global__ __launch_bounds__(512, 1) void final_gemm_kernel(
    const unsigned short* __restrict__ A,     // q_bf [16384][1024]
    const unsigned short* __restrict__ Beff,  // [4][1024][1024] bf16
    const float* __restrict__ beff,           // [4][1024]
    float* __restrict__ out) {
  __shared__ unsigned short As[4][256][32];
  __shared__ unsigned short Bs[4][256][32];
  const int flat = blockIdx.y * 4 + blockIdx.x;  // 256, %8==0
  const int swz = (flat & 7) * 32 + (flat >> 3);
  const int bm = swz >> 2, bn = swz & 3;
  const int b = bm >> 4;  // 16 row-tiles of 256 per batch
  gemm256_body<false>(A, Beff + (size_t)b * 1048576, beff + b * 1024, out, bm, bn, As, Bs);
}

// ============ kv partials: kvp[chunk][b*16+h][i][j] = sum_{s in chunk} kh[s][i]*vh[s][j] ============
__global__ __launch_bounds__(256) void kv_part_kernel(const unsigned short* __restrict__ kh,
                                                      const unsigned short* __restrict__ vh,
                                                      float* __restrict__ kvp) {
  const int chunk = blockIdx.x, h = blockIdx.y, b = blockIdx.z;
  __shared__ unsigned short khT[64][264];
  __shared__ unsigned short vhT[64][264];
  const int tid = threadIdx.x, wid = tid >> 6, lane = tid & 63;
  const int fr = lane & 15, fk = (lane >> 4) * 8, g4 = (lane >> 4) * 4;

  const int jb = tid & 7, sb = tid >> 3;
  const size_t base = ((size_t)b * 4096 + chunk * 256) * 1024 + h * 64;
  {
    ushort8 rk[8], rv[8];
#pragma unroll
    for (int u = 0; u < 8; ++u) {
      rk[u] = *(const ushort8*)(kh + base + (size_t)(sb * 8 + u) * 1024 + jb * 8);
      rv[u] = *(const ushort8*)(vh + base + (size_t)(sb * 8 + u) * 1024 + jb * 8);
    }
#pragma unroll
    for (int jj = 0; jj < 8; ++jj) {
      ushort8 ck, cv;
#pragma unroll
      for (int u = 0; u < 8; ++u) { ck[u] = rk[u][jj]; cv[u] = rv[u][jj]; }
      *(ushort8*)&khT[jb * 8 + jj][sb * 8] = ck;
      *(ushort8*)&vhT[jb * 8 + jj][sb * 8] = cv;
    }
  }
  __syncthreads();

  f32x4 acc2[4];
#pragma unroll
  for (int n = 0; n < 4; ++n) acc2[n] = (f32x4){0.f, 0.f, 0.f, 0.f};
#pragma unroll
  for (int ks = 0; ks < 8; ++ks) {
    bf16x8 a2 = *(const bf16x8*)&khT[wid * 16 + fr][ks * 32 + fk];
    bf16x8 b2[4];
#pragma unroll
    for (int jt = 0; jt < 4; ++jt) b2[jt] = *(const bf16x8*)&vhT[jt * 16 + fr][ks * 32 + fk];
#pragma unroll
    for (int jt = 0; jt < 4; ++jt)
      acc2[jt] = __builtin_amdgcn_mfma_f32_16x16x32_bf16(a2, b2[jt], acc2[jt], 0, 0, 0);
  }
  float* dst = kvp + ((size_t)chunk * 64 + b * 16 + h) * 4096;
#pragma unroll
  for (int jt = 0; jt < 4; ++jt)
#pragma unroll
    for (int jj = 0; jj < 4; ++jj)
      dst[(wid * 16 + g4 + jj) * 64 + jt * 16 + fr] = acc2[jt][jj];
}

// ============ weff (+fused chunk reduce): Beff[b][h*64+j][d] = sum_i Wq[h*64+i][d]*kv[b,h,i,j] ============
__global__ __launch_bounds__(256) void weff_kernel(
    const unsigned short* __restrict__ Wq,   // bf16 [1024][1024]
    const float* __restrict__ bq,            // [1024]
    const float* __restrict__ kvp,           // [16][64][64][64] f32 partials
    unsigned short* __restrict__ Beff,       // [4][1024][1024] bf16
    float* __restrict__ beff) {              // [4][1024]
  const int dt = blockIdx.x, h = blockIdx.y, b = blockIdx.z;
  __shared__ float kvS[64 * 64];
  __shared__ float WqF[64 * 128];
  const int tid = threadIdx.x;

  const float* kvsrc = kvp + (size_t)(b * 16 + h) * 4096;
  for (int e = tid; e < 4096; e += 256) {
    float s = 0.f;
#pragma unroll
    for (int c = 0; c < 16; ++c) s += kvsrc[(size_t)c * 64 * 4096 + e];
    kvS[e] = s;
  }
  {
    int i = tid >> 2, dseg = tid & 3;
    const unsigned short* src = Wq + (size_t)(h * 64 + i) * 1024 + dt * 128 + dseg * 32;
    float* dst = &WqF[i * 128 + dseg * 32];
#pragma unroll
    for (int w = 0; w < 4; ++w) {
      ushort8 vv = ((const ushort8*)src)[w];
#pragma unroll
      for (int u = 0; u < 8; ++u) dst[w * 8 + u] = bf2f(vv[u]);
    }
  }
  __syncthreads();

  const int tj = tid & 63, tg = tid >> 6;
  float o[32];
#pragma unroll
  for (int dd = 0; dd < 32; ++dd) o[dd] = 0.f;
  for (int i = 0; i < 64; ++i) {
    float kvv = kvS[i * 64 + tj];
    const float* wr = &WqF[i * 128 + tg * 32];
#pragma unroll
    for (int dd = 0; dd < 32; ++dd) o[dd] += wr[dd] * kvv;
  }
  unsigned short* dstB = Beff + ((size_t)(b * 1024 + h * 64 + tj)) * 1024 + dt * 128 + tg * 32;
#pragma unroll
  for (int w = 0; w < 4; ++w) {
    ushort8 ov;
#pragma unroll
    for (int u = 0; u < 8; ++u) ov[u] = f2bf(o[w * 8 + u]);
    ((ushort8*)dstB)[w] = ov;
  }
  if (tg == 0 && dt == 0) {
    float s = 0.f;
    for (int i = 0; i < 64; ++i) s += bq[h * 64 + i] * kvS[i * 64 + tj];
    beff[b * 1024 + h * 64 + tj] = s;
  }
}

extern "C" void kernel_launch(void* const* d_in, const int* in_sizes, int n_in,
                              void* d_out, int out_size, void* d_ws, size_t ws_size,
                              hipStream_t stream) {
  const float* q = (const float*)d_in[0];
  const float* k = (const float*)d_in[1];
  const float* v = (const float*)d_in[2];
  const float* Wq = (const float*)d_in[3];
  const float* bq = (const float*)d_in[4];
  const float* Wk = (const float*)d_in[5];
  const float* bk = (const float*)d_in[6];
  const float* Wv = (const float*)d_in[7];
  const float* bv = (const float*)d_in[8];
  float* out = (float*)d_out;

  const size_t NE = (size_t)16384 * 1024;
  const size_t MB = 1048576;

  char* ws = (char*)d_ws;
  unsigned short* S0 = (unsigned short*)(ws + 0 * MB);    // k_bf; later kvp (16MB) + Beff (8MB @ +16MB)
  unsigned short* S1 = (unsigned short*)(ws + 32 * MB);   // v_bf; later q_bf
  unsigned short* kh = (unsigned short*)(ws + 64 * MB);   // 32 MB
  unsigned short* vh = (unsigned short*)(ws + 96 * MB);   // 32 MB
  unsigned short* Wqb = (unsigned short*)(ws + 128 * MB); // 2 MB
  unsigned short* Wkb = (unsigned short*)(ws + 130 * MB); // 2 MB
  unsigned short* Wvb = (unsigned short*)(ws + 132 * MB); // 2 MB
  float* beff = (float*)(ws + 134 * MB);                  // 16 KB
  float* kvp = (float*)S0;                                // 16 MB (k_bf dead by then)
  unsigned short* Beff = (unsigned short*)(ws + 16 * MB); // 8 MB

  // 1) k,v and weights -> bf16
  cvt2_kernel<<<dim3(8192, 2), 256, 0, stream>>>(k, v, S0, S1, (int)(NE / 8));
  cvt3w_kernel<<<dim3(512, 3), 256, 0, stream>>>(Wq, Wk, Wv, Wqb, Wkb, Wvb, 131072);

  // 2) projections + bias + L2 norm (256^2 4-phase, counted vmcnt, XCD-swizzled)
  proj_norm_kernel<<<dim3(4, 64, 2), 512, 0, stream>>>(S0, S1, Wkb, Wvb, bk, bv, kh, vh);

  // 3) q -> bf16 (into v_bf slot, now dead)
  cvt_kernel<<<8192, 256, 0, stream>>>(q, S1, (int)(NE / 8));

  // 4) kv chunk partials (deterministic, into k_bf slot, now dead)
  kv_part_kernel<<<dim3(16, 16, 4), 256, 0, stream>>>(kh, vh, kvp);

  // 5) weff: fused chunk-reduce + Wq-fold -> Beff bf16, beff
  weff_kernel<<<dim3(8, 16, 4), 256, 0, stream>>>(Wqb, bq, kvp, Beff, beff);

  // 6) out = q_bf @ Beff^T + beff (f32 out, 4-phase)
  final_gemm_kernel<<<dim3(4, 64), 512, 0, stream>>>(S1, Beff, beff, out);
}

// Round 11
// 213.608 us; speedup vs baseline: 1.7772x; 1.0902x over previous
//
#include <hip/hip_runtime.h>
#include <hip/hip_bf16.h>
#include <stdint.h>

typedef __attribute__((ext_vector_type(8))) short bf16x8;
typedef __attribute__((ext_vector_type(4))) float f32x4;
typedef __attribute__((ext_vector_type(8))) unsigned short ushort8;

__device__ __forceinline__ float bf2f(unsigned short u) {
  union { unsigned int i; float f; } x; x.i = ((unsigned int)u) << 16; return x.f;
}
__device__ __forceinline__ unsigned short f2bf(float f) {
  union { __hip_bfloat16 h; unsigned short u; } x; x.h = __float2bfloat16(f); return x.u;
}

__device__ __forceinline__ void gload_lds16(const void* g, void* l) {
  __builtin_amdgcn_global_load_lds((__attribute__((address_space(1))) const void*)g,
                                   (__attribute__((address_space(3))) void*)l, 16, 0, 0);
}

// ---------------- f32 -> bf16 converts ----------------
__global__ __launch_bounds__(256) void cvt_kernel(const float* __restrict__ in,
                                                  unsigned short* __restrict__ out,
                                                  int n8) {
  int i = blockIdx.x * 256 + threadIdx.x;
  if (i >= n8) return;
  const float4* p = (const float4*)(in + (size_t)i * 8);
  float4 a = p[0], b = p[1];
  ushort8 o;
  o[0] = f2bf(a.x); o[1] = f2bf(a.y); o[2] = f2bf(a.z); o[3] = f2bf(a.w);
  o[4] = f2bf(b.x); o[5] = f2bf(b.y); o[6] = f2bf(b.z); o[7] = f2bf(b.w);
  *(ushort8*)(out + (size_t)i * 8) = o;
}

__global__ __launch_bounds__(256) void cvt2_kernel(const float* __restrict__ a,
                                                   const float* __restrict__ b,
                                                   unsigned short* __restrict__ oa,
                                                   unsigned short* __restrict__ ob,
                                                   int n8) {
  const float* in = blockIdx.y ? b : a;
  unsigned short* out = blockIdx.y ? ob : oa;
  int i = blockIdx.x * 256 + threadIdx.x;
  if (i >= n8) return;
  const float4* p = (const float4*)(in + (size_t)i * 8);
  float4 x = p[0], y = p[1];
  ushort8 o;
  o[0] = f2bf(x.x); o[1] = f2bf(x.y); o[2] = f2bf(x.z); o[3] = f2bf(x.w);
  o[4] = f2bf(y.x); o[5] = f2bf(y.y); o[6] = f2bf(y.z); o[7] = f2bf(y.w);
  *(ushort8*)(out + (size_t)i * 8) = o;
}

__global__ __launch_bounds__(256) void cvt3w_kernel(const float* __restrict__ a,
                                                    const float* __restrict__ b,
                                                    const float* __restrict__ c,
                                                    unsigned short* __restrict__ oa,
                                                    unsigned short* __restrict__ ob,
                                                    unsigned short* __restrict__ oc,
                                                    int n8) {
  const float* in = blockIdx.y == 0 ? a : blockIdx.y == 1 ? b : c;
  unsigned short* out = blockIdx.y == 0 ? oa : blockIdx.y == 1 ? ob : oc;
  int i = blockIdx.x * 256 + threadIdx.x;
  if (i >= n8) return;
  const float4* p = (const float4*)(in + (size_t)i * 8);
  float4 x = p[0], y = p[1];
  ushort8 o;
  o[0] = f2bf(x.x); o[1] = f2bf(x.y); o[2] = f2bf(x.z); o[3] = f2bf(x.w);
  o[4] = f2bf(y.x); o[5] = f2bf(y.y); o[6] = f2bf(y.z); o[7] = f2bf(y.w);
  *(ushort8*)(out + (size_t)i * 8) = o;
}

// ======================================================================
// Shared 4-phase 256x256 GEMM K-loop. acc[8][4] += A[256,1024] @ B[256,1024]^T
// tile at (bm,bn). Waits only at P2/P4 with vmcnt(4) (FIFO-verified: each
// staged unit guaranteed 2 phases after issue, consumed 3 after). No explicit
// lgkmcnt — compiler emits fine-grained waits for the ds_read->MFMA deps.
// Swizzle (0-conflict, r9/r10-verified): phys granule = logical ^ ((row>>1)&3).
// ======================================================================
__device__ __forceinline__ void gemm256_loop(
    const unsigned short* __restrict__ A,
    const unsigned short* __restrict__ B,
    int bm, int bn,
    unsigned short (*As)[256][32], unsigned short (*Bs)[256][32],
    f32x4 (*acc)[4]) {
  const int tid = threadIdx.x;
  const int widx = tid >> 6, lane = tid & 63;
  const int wr = widx >> 2, wc = widx & 3;
  const int fr = lane & 15, fkg = lane >> 4;
  const int pgo = (fkg ^ ((fr >> 1) & 3)) * 8;          // swizzled read granule
  const int srow = lane >> 2;                           // staging row-in-16
  const int sg = ((lane & 3) ^ ((lane >> 3) & 3)) * 8;  // swizzled source granule

  const size_t abase = (size_t)(bm * 256) * 1024;
  const size_t bbase = (size_t)(bn * 256) * 1024;

  bf16x8 aF[8], bF[4];

#define STG_A(bufi, kh, kt)                                                                \
  {                                                                                        \
    gload_lds16(A + abase + (size_t)(widx * 16 + srow) * 1024 + (kt) * 64 + (kh) * 32 + sg,\
                &As[(bufi) * 2 + (kh)][widx * 16][0]);                                     \
    gload_lds16(A + abase + (size_t)(128 + widx * 16 + srow) * 1024 + (kt) * 64 + (kh) * 32 + sg, \
                &As[(bufi) * 2 + (kh)][128 + widx * 16][0]);                               \
  }
#define STG_B(bufi, kh, kt)                                                                \
  {                                                                                        \
    gload_lds16(B + bbase + (size_t)(widx * 16 + srow) * 1024 + (kt) * 64 + (kh) * 32 + sg,\
                &Bs[(bufi) * 2 + (kh)][widx * 16][0]);                                     \
    gload_lds16(B + bbase + (size_t)(128 + widx * 16 + srow) * 1024 + (kt) * 64 + (kh) * 32 + sg, \
                &Bs[(bufi) * 2 + (kh)][128 + widx * 16][0]);                               \
  }
#define LDA(bufi, ks)                                                                      \
  _Pragma("unroll") for (int m = 0; m < 8; ++m)                                            \
      aF[m] = *(const bf16x8*)&As[(bufi) * 2 + (ks)][wr * 128 + m * 16 + fr][pgo];
#define LDBALL(bufi, ks)                                                                   \
  _Pragma("unroll") for (int n = 0; n < 4; ++n)                                            \
      bF[n] = *(const bf16x8*)&Bs[(bufi) * 2 + (ks)][wc * 64 + n * 16 + fr][pgo];
#define MMALL()                                                                            \
  {                                                                                        \
    __builtin_amdgcn_s_setprio(1);                                                         \
    _Pragma("unroll") for (int m = 0; m < 8; ++m)                                          \
        _Pragma("unroll") for (int n = 0; n < 4; ++n)                                      \
            acc[m][n] = __builtin_amdgcn_mfma_f32_16x16x32_bf16(aF[m], bF[n], acc[m][n], 0, 0, 0); \
    __builtin_amdgcn_s_setprio(0);                                                         \
  }
#define BARM() asm volatile("s_barrier" ::: "memory")
#define VMW(N) asm volatile("s_waitcnt vmcnt(" #N ")" ::: "memory")

  // prologue: (b0,k0,t0), (b0,k1,t0), (b1,k0,t1); wait first 2 units
  STG_A(0, 0, 0); STG_B(0, 0, 0);
  STG_A(0, 1, 0); STG_B(0, 1, 0);
  STG_A(1, 0, 1); STG_B(1, 0, 1);
  VMW(4);
  BARM();

  for (int i = 0; i < 8; ++i) {
    const int t1s = 2 * i + 1, u0 = 2 * i + 2, u1 = 2 * i + 3;
    const bool st = (i < 7);
    // P1: compute (b0,k0); stage (b1,k1) <- t1s
    LDA(0, 0); LDBALL(0, 0); STG_A(1, 1, t1s); STG_B(1, 1, t1s);
    BARM(); MMALL(); BARM();
    // P2: compute (b0,k1); stage (b0,k0) <- u0 ; wait
    LDA(0, 1); LDBALL(0, 1); if (st) { STG_A(0, 0, u0); STG_B(0, 0, u0); }
    BARM(); MMALL();
    if (st) { VMW(4); } else { VMW(0); }
    BARM();
    // P3: compute (b1,k0); stage (b0,k1) <- u0
    LDA(1, 0); LDBALL(1, 0); if (st) { STG_A(0, 1, u0); STG_B(0, 1, u0); }
    BARM(); MMALL(); BARM();
    // P4: compute (b1,k1); stage (b1,k0) <- u1 ; wait
    LDA(1, 1); LDBALL(1, 1); if (st) { STG_A(1, 0, u1); STG_B(1, 0, u1); }
    BARM(); MMALL();
    if (st) { VMW(4); } else { VMW(0); }
    BARM();
  }
#undef STG_A
#undef STG_B
#undef LDA
#undef LDBALL
#undef MMALL
#undef BARM
#undef VMW
}

// ---------------- proj pair: kh = norm(k@Wk^T+bk), vh = norm(v@Wv^T+bv) ----------------
__global__ __launch_bounds__(512, 1) void proj_norm_kernel(
    const unsigned short* __restrict__ A0, const unsigned short* __restrict__ A1,
    const unsigned short* __restrict__ B0, const unsigned short* __restrict__ B1,
    const float* __restrict__ bias0, const float* __restrict__ bias1,
    unsigned short* __restrict__ C0, unsigned short* __restrict__ C1) {
  __shared__ unsigned short As[4][256][32];
  __shared__ unsigned short Bs[4][256][32];
  const int flat = (blockIdx.z * 64 + blockIdx.y) * 4 + blockIdx.x;  // 512, %8==0
  const int swz = (flat & 7) * 64 + (flat >> 3);                     // bijective
  const int zz = swz >> 8;
  const int rem = swz & 255;
  const int bm = rem >> 2, bn = rem & 3;
  const unsigned short* A = zz ? A1 : A0;
  const unsigned short* B = zz ? B1 : B0;
  const float* bias = zz ? bias1 : bias0;
  unsigned short* C = zz ? C1 : C0;

  f32x4 acc[8][4];
#pragma unroll
  for (int m = 0; m < 8; ++m)
#pragma unroll
    for (int n = 0; n < 4; ++n) acc[m][n] = (f32x4){0.f, 0.f, 0.f, 0.f};

  gemm256_loop(A, B, bm, bn, As, Bs, acc);

  const int tid = threadIdx.x, widx = tid >> 6, lane = tid & 63;
  const int wr = widx >> 2, wc = widx & 3;
  const int fr = lane & 15, g4 = (lane >> 4) * 4;

  float bsv[4];
#pragma unroll
  for (int n = 0; n < 4; ++n) bsv[n] = bias[bn * 256 + wc * 64 + n * 16 + fr];
#pragma unroll
  for (int m = 0; m < 8; ++m) {
    float val[4][4];  // [n][j]
    float inv[4];
#pragma unroll
    for (int j = 0; j < 4; ++j) {
      float s = 0.f;
#pragma unroll
      for (int n = 0; n < 4; ++n) {
        val[n][j] = acc[m][n][j] + bsv[n];
        s += val[n][j] * val[n][j];
      }
      s += __shfl_xor(s, 1); s += __shfl_xor(s, 2);
      s += __shfl_xor(s, 4); s += __shfl_xor(s, 8);
      inv[j] = 1.f / fmaxf(sqrtf(s), 1e-12f);
    }
#pragma unroll
    for (int n = 0; n < 4; ++n) {
      const int col = bn * 256 + wc * 64 + n * 16 + fr;
#pragma unroll
      for (int j = 0; j < 4; ++j) {
        const int row = bm * 256 + wr * 128 + m * 16 + g4 + j;
        C[(size_t)row * 1024 + col] = f2bf(val[n][j] * inv[j]);
      }
    }
  }
}

// ---------------- final fold: out = (q@Wq^T + bq) @ kv per head (f32 out) ----------------
// GEMM1 (K=1024) into acc; qp -> LDS (bias added, bf16, swizzled); GEMM2 (K=64)
// against kvT staged in the top 32 KB of a 160 KB LDS block. No Beff, no weff.
__global__ __launch_bounds__(512, 1) void final_fold_kernel(
    const unsigned short* __restrict__ A,    // q_bf [16384][1024]
    const unsigned short* __restrict__ Wqb,  // bf16 [1024][1024]
    const float* __restrict__ bq,            // [1024]
    const unsigned short* __restrict__ kvT,  // bf16 [4][16][64][64]  ([b][h][j][i])
    float* __restrict__ out) {
  __shared__ __align__(16) unsigned char smem[163840];
  unsigned short (*As)[256][32] = (unsigned short (*)[256][32])smem;
  unsigned short (*Bs)[256][32] = (unsigned short (*)[256][32])(smem + 65536);

  const int flat = blockIdx.y * 4 + blockIdx.x;  // 256, %8==0
  const int swz = (flat & 7) * 32 + (flat >> 3);
  const int bm = swz >> 2, bn = swz & 3;
  const int bB = bm >> 4;  // batch

  const int tid = threadIdx.x, widx = tid >> 6, lane = tid & 63;
  const int wr = widx >> 2, wc = widx & 3;
  const int fr = lane & 15, fkg = lane >> 4, g4 = fkg * 4;

  // stage kvT for this block's 4 heads into smem[131072..163839] (swizzled)
#pragma unroll
  for (int t = 0; t < 4; ++t) {
    int unit = t * 512 + tid;         // 0..2047
    int h = unit >> 9;                // 0..3
    int jr = (unit >> 3) & 63;        // j row
    int g = unit & 7;                 // 16B granule (8 per 128B row)
    ushort8 vvv = *(const ushort8*)(kvT +
        ((size_t)(bB * 16 + bn * 4 + h) * 4096) + jr * 64 + g * 8);
    *(ushort8*)(smem + 131072 + h * 8192 + jr * 128 + ((g ^ (jr & 7)) * 16)) = vvv;
  }
  __syncthreads();

  f32x4 acc[8][4];
#pragma unroll
  for (int m = 0; m < 8; ++m)
#pragma unroll
    for (int n = 0; n < 4; ++n) acc[m][n] = (f32x4){0.f, 0.f, 0.f, 0.f};

  gemm256_loop(A, Wqb, bm, bn, As, Bs, acc);

  // qp -> LDS: per-wave 16KB region [128 rows][64 i] bf16, granule-XOR swizzle
  {
    float bsv[4];
#pragma unroll
    for (int n = 0; n < 4; ++n) bsv[n] = bq[bn * 256 + wc * 64 + n * 16 + fr];
#pragma unroll
    for (int m = 0; m < 8; ++m)
#pragma unroll
      for (int n = 0; n < 4; ++n)
#pragma unroll
        for (int j = 0; j < 4; ++j) {
          float v = acc[m][n][j] + bsv[n];
          int r = m * 16 + g4 + j;   // local row 0..127
          int c = n * 16 + fr;       // local i 0..63
          *(unsigned short*)(smem + widx * 16384 + r * 128 +
                             (((c >> 3) ^ (r & 7)) * 16) + (c & 7) * 2) = f2bf(v);
        }
  }
  __syncthreads();

  // GEMM2: out_wave[128x64] = qp_wave[128x64] @ kv[head wc][64x64]
  f32x4 acc2[8][4];
#pragma unroll
  for (int m = 0; m < 8; ++m)
#pragma unroll
    for (int n = 0; n < 4; ++n) acc2[m][n] = (f32x4){0.f, 0.f, 0.f, 0.f};

#pragma unroll
  for (int ks = 0; ks < 2; ++ks) {
    bf16x8 a2[8], b2[4];
#pragma unroll
    for (int m = 0; m < 8; ++m)
      a2[m] = *(const bf16x8*)(smem + widx * 16384 + (m * 16 + fr) * 128 +
                               (((ks * 4 + fkg) ^ (fr & 7)) * 16));
#pragma unroll
    for (int n = 0; n < 4; ++n)
      b2[n] = *(const bf16x8*)(smem + 131072 + wc * 8192 + (n * 16 + fr) * 128 +
                               (((ks * 4 + fkg) ^ (fr & 7)) * 16));
#pragma unroll
    for (int m = 0; m < 8; ++m)
#pragma unroll
      for (int n = 0; n < 4; ++n)
        acc2[m][n] = __builtin_amdgcn_mfma_f32_16x16x32_bf16(a2[m], b2[n], acc2[m][n], 0, 0, 0);
  }

#pragma unroll
  for (int n = 0; n < 4; ++n) {
    const int col = bn * 256 + wc * 64 + n * 16 + fr;
#pragma unroll
    for (int m = 0; m < 8; ++m)
#pragma unroll
      for (int j = 0; j < 4; ++j) {
        const int row = bm * 256 + wr * 128 + m * 16 + g4 + j;
        out[(size_t)row * 1024 + col] = acc2[m][n][j];
      }
  }
}

// ============ kv partials: kvp[chunk][b*16+h][i][j] = sum_{s in chunk} kh[s][i]*vh[s][j] ============
__global__ __launch_bounds__(256) void kv_part_kernel(const unsigned short* __restrict__ kh,
                                                      const unsigned short* __restrict__ vh,
                                                      float* __restrict__ kvp) {
  const int chunk = blockIdx.x, h = blockIdx.y, b = blockIdx.z;
  __shared__ unsigned short khT[64][264];
  __shared__ unsigned short vhT[64][264];
  const int tid = threadIdx.x, wid = tid >> 6, lane = tid & 63;
  const int fr = lane & 15, fk = (lane >> 4) * 8, g4 = (lane >> 4) * 4;

  const int jb = tid & 7, sb = tid >> 3;
  const size_t base = ((size_t)b * 4096 + chunk * 256) * 1024 + h * 64;
  {
    ushort8 rk[8], rv[8];
#pragma unroll
    for (int u = 0; u < 8; ++u) {
      rk[u] = *(const ushort8*)(kh + base + (size_t)(sb * 8 + u) * 1024 + jb * 8);
      rv[u] = *(const ushort8*)(vh + base + (size_t)(sb * 8 + u) * 1024 + jb * 8);
    }
#pragma unroll
    for (int jj = 0; jj < 8; ++jj) {
      ushort8 ck, cv;
#pragma unroll
      for (int u = 0; u < 8; ++u) { ck[u] = rk[u][jj]; cv[u] = rv[u][jj]; }
      *(ushort8*)&khT[jb * 8 + jj][sb * 8] = ck;
      *(ushort8*)&vhT[jb * 8 + jj][sb * 8] = cv;
    }
  }
  __syncthreads();

  f32x4 acc2[4];
#pragma unroll
  for (int n = 0; n < 4; ++n) acc2[n] = (f32x4){0.f, 0.f, 0.f, 0.f};
#pragma unroll
  for (int ks = 0; ks < 8; ++ks) {
    bf16x8 a2 = *(const bf16x8*)&khT[wid * 16 + fr][ks * 32 + fk];
    bf16x8 b2[4];
#pragma unroll
    for (int jt = 0; jt < 4; ++jt) b2[jt] = *(const bf16x8*)&vhT[jt * 16 + fr][ks * 32 + fk];
#pragma unroll
    for (int jt = 0; jt < 4; ++jt)
      acc2[jt] = __builtin_amdgcn_mfma_f32_16x16x32_bf16(a2, b2[jt], acc2[jt], 0, 0, 0);
  }
  float* dst = kvp + ((size_t)chunk * 64 + b * 16 + h) * 4096;
#pragma unroll
  for (int jt = 0; jt < 4; ++jt)
#pragma unroll
    for (int jj = 0; jj < 4; ++jj)
      dst[(wid * 16 + g4 + jj) * 64 + jt * 16 + fr] = acc2[jt][jj];
}

// ============ kvT reduce: kvT[bh][j][i] = bf16( sum_c kvp[c][bh][i][j] ) ============
__global__ __launch_bounds__(256) void kvt_reduce_kernel(const float* __restrict__ kvp,
                                                         unsigned short* __restrict__ kvT) {
  const int bh = blockIdx.x;  // 0..63
  for (int e = threadIdx.x; e < 4096; e += 256) {
    float s = 0.f;
#pragma unroll
    for (int c = 0; c < 16; ++c) s += kvp[((size_t)c * 64 + bh) * 4096 + e];
    int i = e >> 6, j = e & 63;
    kvT[(size_t)bh * 4096 + j * 64 + i] = f2bf(s);
  }
}

extern "C" void kernel_launch(void* const* d_in, const int* in_sizes, int n_in,
                              void* d_out, int out_size, void* d_ws, size_t ws_size,
                              hipStream_t stream) {
  const float* q = (const float*)d_in[0];
  const float* k = (const float*)d_in[1];
  const float* v = (const float*)d_in[2];
  const float* Wq = (const float*)d_in[3];
  const float* bq = (const float*)d_in[4];
  const float* Wk = (const float*)d_in[5];
  const float* bk = (const float*)d_in[6];
  const float* Wv = (const float*)d_in[7];
  const float* bv = (const float*)d_in[8];
  float* out = (float*)d_out;

  const size_t NE = (size_t)16384 * 1024;
  const size_t MB = 1048576;

  char* ws = (char*)d_ws;
  unsigned short* S0 = (unsigned short*)(ws + 0 * MB);    // k_bf; later kvp (16MB)
  unsigned short* S1 = (unsigned short*)(ws + 32 * MB);   // v_bf; later q_bf
  unsigned short* kh = (unsigned short*)(ws + 64 * MB);   // 32 MB
  unsigned short* vh = (unsigned short*)(ws + 96 * MB);   // 32 MB
  unsigned short* Wqb = (unsigned short*)(ws + 128 * MB); // 2 MB
  unsigned short* Wkb = (unsigned short*)(ws + 130 * MB); // 2 MB
  unsigned short* Wvb = (unsigned short*)(ws + 132 * MB); // 2 MB
  unsigned short* kvT = (unsigned short*)(ws + 134 * MB); // 512 KB
  float* kvp = (float*)S0;                                // 16 MB (k_bf dead by then)

  // 1) k,v and weights -> bf16
  cvt2_kernel<<<dim3(8192, 2), 256, 0, stream>>>(k, v, S0, S1, (int)(NE / 8));
  cvt3w_kernel<<<dim3(512, 3), 256, 0, stream>>>(Wq, Wk, Wv, Wqb, Wkb, Wvb, 131072);

  // 2) projections + bias + L2 norm (256^2 4-phase, waits at P2/P4 only)
  proj_norm_kernel<<<dim3(4, 64, 2), 512, 0, stream>>>(S0, S1, Wkb, Wvb, bk, bv, kh, vh);

  // 3) q -> bf16 (into v_bf slot, now dead)
  cvt_kernel<<<8192, 256, 0, stream>>>(q, S1, (int)(NE / 8));

  // 4) kv chunk partials (deterministic, into k_bf slot, now dead)
  kv_part_kernel<<<dim3(16, 16, 4), 256, 0, stream>>>(kh, vh, kvp);

  // 5) reduce partials -> kvT bf16 [b][h][j][i]
  kvt_reduce_kernel<<<64, 256, 0, stream>>>(kvp, kvT);

  // 6) out = (q@Wq^T + bq) @ kv  (folded, f32 out)
  final_fold_kernel<<<dim3(4, 64), 512, 0, stream>>>(S1, Wqb, bq, kvT, out);
}